// Round 12
// baseline (112.938 us; speedup 1.0000x reference)
//
#include <hip/hip_runtime.h>
#include <hip/hip_bf16.h>

typedef __hip_bfloat16 bf16;
typedef __attribute__((ext_vector_type(8))) short short8;
typedef __attribute__((ext_vector_type(4))) float f32x4;

#define SBAR() asm volatile("s_barrier" ::: "memory")
#define VMCNT8() asm volatile("s_waitcnt vmcnt(8)" ::: "memory")
#define VMCNT6() asm volatile("s_waitcnt vmcnt(6)" ::: "memory")
#define VMCNT2() asm volatile("s_waitcnt vmcnt(2)" ::: "memory")
#define VMCNT0() asm volatile("s_waitcnt vmcnt(0)" ::: "memory")

__device__ __forceinline__ void gload_lds16(const bf16* g, bf16* l) {
  __builtin_amdgcn_global_load_lds(
      (const __attribute__((address_space(1))) unsigned int*)g,
      (__attribute__((address_space(3))) unsigned int*)l, 16, 0, 0);
}

// Stage one 128x64 half-tile (row-major, ld=1024) into a linear 16KB LDS slot.
// Global source col is XOR-swizzled so swizzled LDS reads are conflict-free.
__device__ __forceinline__ void stage_half(const bf16* gbase, bf16* slot, int tid) {
  const int r = tid >> 3;                    // 0..63
  const int c = ((tid & 7) ^ (r & 7)) << 3;  // swizzled 16B chunk
  gload_lds16(gbase + (long)r * 1024 + c, slot + tid * 8);
  gload_lds16(gbase + (long)(r + 64) * 1024 + c, slot + 4096 + tid * 8);
}

// Same, for 256-thread blocks (4 passes of 32 rows).
__device__ __forceinline__ void stage_tile128_t256(const bf16* gbase, bf16* slot,
                                                   int t) {
#pragma unroll
  for (int p = 0; p < 4; ++p) {
    const int r = p * 32 + (t >> 3);
    const int c = ((t & 7) ^ (r & 7)) << 3;
    gload_lds16(gbase + (long)r * 1024 + c, slot + p * 2048 + t * 8);
  }
}

// Swizzled fragment read: logical (row, 16B-chunk c16) of a [128][64] half-slot.
__device__ __forceinline__ short8 lds_frag(const bf16* slot, int row, int c16) {
  return *(const short8*)(slot + row * 64 + ((c16 ^ (row & 7)) << 3));
}

#define MFMA16(A_, B_, acc, mo, no)                                               \
  _Pragma("unroll") for (int m = 0; m < 4; ++m)                                   \
      _Pragma("unroll") for (int n = 0; n < 2; ++n)                               \
          _Pragma("unroll") for (int ks = 0; ks < 2; ++ks)                        \
              acc[m + (mo)][n + (no)] = __builtin_amdgcn_mfma_f32_16x16x32_bf16(  \
                  A_[m][ks], B_[n][ks], acc[m + (mo)][n + (no)], 0, 0, 0);

// ======== 256x256-tile m201-style 8-phase loop (2 K-tiles / iteration).
// One half-tile staged per phase; vmcnt(6) (= 3 half-tiles in flight) only at
// phases 4 and 8. Reads front-loaded: ph1 reads a01+b01+b23 of the even tile,
// ph2 reads a47 (so even slots are stage-free from ph2/ph3 on); same at ph5/ph6
// for the odd tile. Slot-liveness: every stage targets a slot whose last-reading
// phase has closed (2nd barrier passed). Slots: A/B x {even h0, even h1,
// odd h0, odd h1} at +0/+8192/+16384/+24576.
#define LOOP256(Ag, Bg, sA, sB, acc)                                              \
  {                                                                               \
    stage_half(Ag, sA, tid);                       /* A0h0 */                     \
    stage_half(Ag + 128 * 1024, sA + 8192, tid);   /* A0h1 */                     \
    stage_half(Bg, sB, tid);                       /* B0h0 */                     \
    stage_half(Bg + 128 * 1024, sB + 8192, tid);   /* B0h1 */                     \
    stage_half(Ag + 64, sA + 16384, tid);              /* A1h0 */                 \
    stage_half(Ag + 128 * 1024 + 64, sA + 24576, tid); /* A1h1 */                 \
    stage_half(Bg + 64, sB + 16384, tid);              /* B1h0 */                 \
    VMCNT6();  /* tile 0 landed; A1h0,A1h1,B1h0 in flight */                      \
    SBAR();                                                                       \
    const int brb = (wc & 1) * 64;                                                \
    const bf16* AsE = sA + wr * 8192;                                             \
    const bf16* AsO = sA + (2 + wr) * 8192;                                       \
    const bf16* BsE = sB + (wc >> 1) * 8192;                                      \
    const bf16* BsO = sB + (2 + (wc >> 1)) * 8192;                                \
    short8 a01[4][2], a47[4][2], b01[2][2], b23[2][2];                            \
    for (int it = 0; it < 8; ++it) {                                              \
      const int t = it * 2;                                                       \
      /* ph1: read a01,b01,b23 (even tile); stage B(t+1)h1; MFMA m0-3 x n0-1 */   \
      _Pragma("unroll") for (int m = 0; m < 4; ++m)                               \
          _Pragma("unroll") for (int ks = 0; ks < 2; ++ks)                        \
              a01[m][ks] = lds_frag(AsE, m * 16 + lr, c16 + ks * 4);              \
      _Pragma("unroll") for (int n = 0; n < 2; ++n)                               \
          _Pragma("unroll") for (int ks = 0; ks < 2; ++ks) {                      \
        b01[n][ks] = lds_frag(BsE, brb + n * 16 + lr, c16 + ks * 4);              \
        b23[n][ks] = lds_frag(BsE, brb + (n + 2) * 16 + lr, c16 + ks * 4);        \
      }                                                                           \
      stage_half(Bg + 128 * 1024 + (t + 1) * 64, sB + 24576, tid);                \
      SBAR();                                                                     \
      __builtin_amdgcn_s_setprio(1);                                              \
      MFMA16(a01, b01, acc, 0, 0);                                                \
      __builtin_amdgcn_s_setprio(0);                                              \
      SBAR();                                                                     \
      /* ph2: read a47 (even); stage B(t+2)h0; MFMA m0-3 x n2-3 */                \
      _Pragma("unroll") for (int m = 0; m < 4; ++m)                               \
          _Pragma("unroll") for (int ks = 0; ks < 2; ++ks)                        \
              a47[m][ks] = lds_frag(AsE, (m + 4) * 16 + lr, c16 + ks * 4);        \
      if (t + 2 < 16) stage_half(Bg + (t + 2) * 64, sB, tid);                     \
      SBAR();                                                                     \
      __builtin_amdgcn_s_setprio(1);                                              \
      MFMA16(a01, b23, acc, 0, 2);                                                \
      __builtin_amdgcn_s_setprio(0);                                              \
      SBAR();                                                                     \
      /* ph3: stage A(t+2)h0; MFMA m4-7 x n2-3 */                                 \
      if (t + 2 < 16) stage_half(Ag + (t + 2) * 64, sA, tid);                     \
      SBAR();                                                                     \
      __builtin_amdgcn_s_setprio(1);                                              \
      MFMA16(a47, b23, acc, 4, 2);                                                \
      __builtin_amdgcn_s_setprio(0);                                              \
      SBAR();                                                                     \
      /* ph4: stage A(t+2)h1; vmcnt(6) -> tile t+1 landed; MFMA m4-7 x n0-1 */    \
      if (t + 2 < 16) {                                                           \
        stage_half(Ag + 128 * 1024 + (t + 2) * 64, sA + 8192, tid);               \
        VMCNT6();                                                                 \
      } else {                                                                    \
        VMCNT0();                                                                 \
      }                                                                           \
      SBAR();                                                                     \
      __builtin_amdgcn_s_setprio(1);                                              \
      MFMA16(a47, b01, acc, 4, 0);                                                \
      __builtin_amdgcn_s_setprio(0);                                              \
      SBAR();                                                                     \
      /* ph5: read a01,b01,b23 (odd tile); stage B(t+2)h1; MFMA m0-3 x n0-1 */    \
      _Pragma("unroll") for (int m = 0; m < 4; ++m)                               \
          _Pragma("unroll") for (int ks = 0; ks < 2; ++ks)                        \
              a01[m][ks] = lds_frag(AsO, m * 16 + lr, c16 + ks * 4);              \
      _Pragma("unroll") for (int n = 0; n < 2; ++n)                               \
          _Pragma("unroll") for (int ks = 0; ks < 2; ++ks) {                      \
        b01[n][ks] = lds_frag(BsO, brb + n * 16 + lr, c16 + ks * 4);              \
        b23[n][ks] = lds_frag(BsO, brb + (n + 2) * 16 + lr, c16 + ks * 4);        \
      }                                                                           \
      if (t + 2 < 16)                                                             \
        stage_half(Bg + 128 * 1024 + (t + 2) * 64, sB + 8192, tid);               \
      SBAR();                                                                     \
      __builtin_amdgcn_s_setprio(1);                                              \
      MFMA16(a01, b01, acc, 0, 0);                                                \
      __builtin_amdgcn_s_setprio(0);                                              \
      SBAR();                                                                     \
      /* ph6: read a47 (odd); stage B(t+3)h0; MFMA m0-3 x n2-3 */                 \
      _Pragma("unroll") for (int m = 0; m < 4; ++m)                               \
          _Pragma("unroll") for (int ks = 0; ks < 2; ++ks)                        \
              a47[m][ks] = lds_frag(AsO, (m + 4) * 16 + lr, c16 + ks * 4);        \
      if (t + 3 < 16) stage_half(Bg + (t + 3) * 64, sB + 16384, tid);             \
      SBAR();                                                                     \
      __builtin_amdgcn_s_setprio(1);                                              \
      MFMA16(a01, b23, acc, 0, 2);                                                \
      __builtin_amdgcn_s_setprio(0);                                              \
      SBAR();                                                                     \
      /* ph7: stage A(t+3)h0; MFMA m4-7 x n2-3 */                                 \
      if (t + 3 < 16) stage_half(Ag + (t + 3) * 64, sA + 16384, tid);             \
      SBAR();                                                                     \
      __builtin_amdgcn_s_setprio(1);                                              \
      MFMA16(a47, b23, acc, 4, 2);                                                \
      __builtin_amdgcn_s_setprio(0);                                              \
      SBAR();                                                                     \
      /* ph8: stage A(t+3)h1; vmcnt(6) -> tile t+2 landed; MFMA m4-7 x n0-1 */    \
      if (t + 3 < 16) {                                                           \
        stage_half(Ag + 128 * 1024 + (t + 3) * 64, sA + 24576, tid);              \
        VMCNT6();                                                                 \
      } else if (t + 2 < 16) {                                                    \
        VMCNT0();                                                                 \
      }                                                                           \
      SBAR();                                                                     \
      __builtin_amdgcn_s_setprio(1);                                              \
      MFMA16(a47, b01, acc, 4, 0);                                                \
      __builtin_amdgcn_s_setprio(0);                                              \
      SBAR();                                                                     \
    }                                                                             \
  }

// ======== 128x256-tile 2-phase loop with read-ahead (round-10/11 proven).
#define LOOP128(Ag, Bg, sA, sB, acc, NTv)                                         \
  {                                                                               \
    stage_half(Ag, sA, tid);                                                      \
    stage_half(Bg, sB, tid);                                                      \
    stage_half(Bg + 128 * 1024, sB + 8192, tid);                                  \
    stage_half(Ag + 64, sA + 8192, tid);                                          \
    VMCNT2();                                                                     \
    SBAR();                                                                       \
    const int brb = (wc & 1) * 64;                                                \
    short8 aq[4][2], b01[2][2], b23[2][2];                                        \
    _Pragma("unroll") for (int m = 0; m < 4; ++m)                                 \
        _Pragma("unroll") for (int ks = 0; ks < 2; ++ks)                          \
            aq[m][ks] = lds_frag(sA, wr * 64 + m * 16 + lr, c16 + ks * 4);        \
    _Pragma("unroll") for (int n = 0; n < 2; ++n)                                 \
        _Pragma("unroll") for (int ks = 0; ks < 2; ++ks)                          \
            b01[n][ks] = lds_frag(sB + (wc >> 1) * 8192, brb + n * 16 + lr,       \
                                  c16 + ks * 4);                                  \
    const int NT = (NTv);                                                         \
    for (int t = 0; t < NT; ++t) {                                                \
      const int rp = t & 1;                                                       \
      const int sp = rp ^ 1;                                                      \
      const bf16* Bs = sB + (rp * 2 + (wc >> 1)) * 8192;                          \
      const bf16* AsN = sA + sp * 8192;                                           \
      const bf16* BsN = sB + (sp * 2 + (wc >> 1)) * 8192;                         \
      _Pragma("unroll") for (int n = 0; n < 2; ++n)                               \
          _Pragma("unroll") for (int ks = 0; ks < 2; ++ks)                        \
              b23[n][ks] = lds_frag(Bs, brb + (n + 2) * 16 + lr, c16 + ks * 4);   \
      if (t + 1 < NT) stage_half(Bg + (t + 1) * 64, sB + sp * 2 * 8192, tid);     \
      SBAR();                                                                     \
      __builtin_amdgcn_s_setprio(1);                                              \
      _Pragma("unroll") for (int m = 0; m < 4; ++m)                               \
          _Pragma("unroll") for (int n = 0; n < 2; ++n)                           \
              _Pragma("unroll") for (int ks = 0; ks < 2; ++ks)                    \
                  acc[m][n] = __builtin_amdgcn_mfma_f32_16x16x32_bf16(            \
                      aq[m][ks], b01[n][ks], acc[m][n], 0, 0, 0);                 \
      __builtin_amdgcn_s_setprio(0);                                              \
      SBAR();                                                                     \
      if (t + 1 < NT)                                                             \
        stage_half(Bg + 128 * 1024 + (t + 1) * 64, sB + (sp * 2 + 1) * 8192, tid);\
      if (t + 2 < NT) {                                                           \
        stage_half(Ag + (t + 2) * 64, sA + rp * 8192, tid);                       \
        VMCNT2();                                                                 \
      } else if (t + 1 < NT) {                                                    \
        VMCNT0();                                                                 \
      }                                                                           \
      SBAR();                                                                     \
      __builtin_amdgcn_s_setprio(1);                                              \
      _Pragma("unroll") for (int m = 0; m < 4; ++m)                               \
          _Pragma("unroll") for (int n = 0; n < 2; ++n)                           \
              _Pragma("unroll") for (int ks = 0; ks < 2; ++ks)                    \
                  acc[m][n + 2] = __builtin_amdgcn_mfma_f32_16x16x32_bf16(        \
                      aq[m][ks], b23[n][ks], acc[m][n + 2], 0, 0, 0);             \
      __builtin_amdgcn_s_setprio(0);                                              \
      if (t + 1 < NT) {                                                           \
        _Pragma("unroll") for (int m = 0; m < 4; ++m)                             \
            _Pragma("unroll") for (int ks = 0; ks < 2; ++ks)                      \
                aq[m][ks] = lds_frag(AsN, wr * 64 + m * 16 + lr, c16 + ks * 4);   \
        _Pragma("unroll") for (int n = 0; n < 2; ++n)                             \
            _Pragma("unroll") for (int ks = 0; ks < 2; ++ks)                      \
                b01[n][ks] = lds_frag(BsN, brb + n * 16 + lr, c16 + ks * 4);      \
      }                                                                           \
      SBAR();                                                                     \
    }                                                                             \
  }

// ---------------- merged G-projection + V'-projection, XCD-affine block map.
__global__ __launch_bounds__(512, 1) void gemm_gv(
    const bf16* __restrict__ xb, const bf16* __restrict__ Mp,
    const bf16* __restrict__ Wp, bf16* __restrict__ G, bf16* __restrict__ VT) {
  __shared__ bf16 smem[65536];
  const int id = blockIdx.x;
  const int tid = threadIdx.x;
  const int lane = tid & 63;
  const int wid = tid >> 6;
  const int wr = wid >> 2;
  const int wc = wid & 3;
  const int lr = lane & 15;
  const int c16 = lane >> 4;
  const long SS = 1024L * 1024;

  const bf16 *Ag, *Bg;
  bf16* C;
  int arow, bcol;
  if (id < 128) {
    const int w = id >> 3;
    const int bm = (id & 7) + 8 * (w >> 2);
    const int bn = w & 3;
    arow = bm * 256;
    bcol = bn * 256;
    Ag = xb + (long)arow * 1024;
    Bg = Mp + (long)bcol * 1024;
    C = G;
  } else {
    const int v = id - 128;
    const int b = v & 7;
    const int gs = (v >> 3) & 3;
    const int ss = v >> 5;
    arow = gs * 256;
    bcol = ss * 256;
    Ag = Wp + (long)arow * 1024;
    Bg = xb + (long)b * SS + (long)bcol * 1024;
    C = VT + (long)b * SS;
  }
  bf16* sA = smem;
  bf16* sB = smem + 32768;

  f32x4 acc[8][4] = {};
  LOOP256(Ag, Bg, sA, sB, acc);

  const int r0 = (lane >> 4) * 4;
#pragma unroll
  for (int m = 0; m < 8; ++m)
#pragma unroll
    for (int n = 0; n < 4; ++n)
#pragma unroll
      for (int r = 0; r < 4; ++r)
        C[(long)(arow + wr * 128 + m * 16 + r0 + r) * 1024 + bcol + wc * 64 + n * 16 + lr] =
            __float2bfloat16(acc[m][n][r]);
}

// ---------------- prep2: full-K small GEMMs (blocks 0-127) overlapped with
// x fp32->bf16 conversion (blocks 128-4223).
__global__ __launch_bounds__(256, 2) void prep2(
    const bf16* __restrict__ wkT, const bf16* __restrict__ wqT,
    const bf16* __restrict__ wo, const bf16* __restrict__ wvT,
    bf16* __restrict__ Mp, bf16* __restrict__ Wp, const float* __restrict__ x,
    bf16* __restrict__ xb) {
  __shared__ bf16 smem[32768];
  const int bid = blockIdx.x;
  const int t = threadIdx.x;

  if (bid >= 128) {  // x conversion
    const long i = (long)(bid - 128) * 2048 + t * 8;
    const float4 a = *(const float4*)&x[i];
    const float4 b = *(const float4*)&x[i + 4];
    const float va[8] = {a.x, a.y, a.z, a.w, b.x, b.y, b.z, b.w};
    union { bf16 h; short s; } u;
    short8 o;
#pragma unroll
    for (int j = 0; j < 8; ++j) { u.h = __float2bfloat16(va[j]); o[j] = u.s; }
    *(short8*)&xb[i] = o;
    return;
  }

  const int mat = bid >> 6;
  const int tile = bid & 63;
  const int bm = tile >> 3, bn = tile & 7;
  const bf16* A = (mat == 0) ? wkT : wo;
  const bf16* B = (mat == 0) ? wqT : wvT;
  bf16* C = (mat == 0) ? Mp : Wp;

  const int lane = t & 63;
  const int wid = t >> 6;
  const int wr = (wid >> 1) * 64;
  const int wc = (wid & 1) * 64;
  const int lr = lane & 15;
  const int c16 = lane >> 4;
  const int arow = bm * 128;
  const int brow = bn * 128;
  const bf16* Ag = A + (long)arow * 1024;
  const bf16* Bg = B + (long)brow * 1024;
  bf16* sA = smem;
  bf16* sB = smem + 16384;

  stage_tile128_t256(Ag, sA, t);
  stage_tile128_t256(Bg, sB, t);
  stage_tile128_t256(Ag + 64, sA + 8192, t);
  stage_tile128_t256(Bg + 64, sB + 8192, t);
  VMCNT8();
  SBAR();

  f32x4 acc[4][4] = {};
  for (int tt = 0; tt < 16; ++tt) {
    const int cur = tt & 1;
    const bf16* As = sA + cur * 8192;
    const bf16* Bs = sB + cur * 8192;
    short8 a[4][2], b[4][2];
#pragma unroll
    for (int m = 0; m < 4; ++m)
#pragma unroll
      for (int ks = 0; ks < 2; ++ks)
        a[m][ks] = lds_frag(As, wr + m * 16 + lr, c16 + ks * 4);
#pragma unroll
    for (int n = 0; n < 4; ++n)
#pragma unroll
      for (int ks = 0; ks < 2; ++ks)
        b[n][ks] = lds_frag(Bs, wc + n * 16 + lr, c16 + ks * 4);
#pragma unroll
    for (int m = 0; m < 4; ++m)
#pragma unroll
      for (int n = 0; n < 4; ++n)
#pragma unroll
        for (int ks = 0; ks < 2; ++ks)
          acc[m][n] = __builtin_amdgcn_mfma_f32_16x16x32_bf16(
              a[m][ks], b[n][ks], acc[m][n], 0, 0, 0);
    SBAR();
    if (tt + 2 < 16) {
      stage_tile128_t256(Ag + (tt + 2) * 64, sA + cur * 8192, t);
      stage_tile128_t256(Bg + (tt + 2) * 64, sB + cur * 8192, t);
      VMCNT8();
    } else if (tt + 1 < 16) {
      VMCNT0();
    }
    SBAR();
  }

#pragma unroll
  for (int m = 0; m < 4; ++m)
#pragma unroll
    for (int n = 0; n < 4; ++n)
#pragma unroll
      for (int r = 0; r < 4; ++r) {
        const int row = arow + wr + m * 16 + (lane >> 4) * 4 + r;
        const int col = brow + wc + n * 16 + lr;
        C[(long)row * 1024 + col] = __float2bfloat16(acc[m][n][r]);
      }
}

// ---------------- scores = BT(G_b, xb_b), causal 128x256 tiles, XCD-affine.
__global__ __launch_bounds__(512, 1) void gemm_sc(
    const bf16* __restrict__ Gall, const bf16* __restrict__ xball,
    bf16* __restrict__ Pall) {
  __shared__ bf16 smem[49152];
  const int id = blockIdx.x;
  const int bz = id & 7;
  int rr = id >> 3, bm = 0;
  while (rr >= bm / 2 + 1) { rr -= bm / 2 + 1; ++bm; }
  const int bn = rr;
  const long SS = 1024L * 1024;
  const bf16* A = Gall + SS * bz;
  const bf16* B = xball + SS * bz;
  const int tid = threadIdx.x;
  const int lane = tid & 63;
  const int wid = tid >> 6;
  const int wr = wid >> 2;
  const int wc = wid & 3;
  const int lr = lane & 15;
  const int c16 = lane >> 4;
  const int bcol = bn * 256;
  const int arow = bm * 128;
  const bf16* Ag = A + (long)arow * 1024;
  const bf16* Bg = B + (long)bcol * 1024;
  bf16* sA = smem;
  bf16* sB = smem + 16384;

  f32x4 acc[4][4] = {};
  LOOP128(Ag, Bg, sA, sB, acc, 16);

  const int r0 = (lane >> 4) * 4;
  bf16* C = Pall + SS * bz;
#pragma unroll
  for (int m = 0; m < 4; ++m)
#pragma unroll
    for (int n = 0; n < 4; ++n)
#pragma unroll
      for (int r = 0; r < 4; ++r)
        C[(long)(arow + wr * 64 + m * 16 + r0 + r) * 1024 + bcol + wc * 64 + n * 16 + lr] =
            __float2bfloat16(acc[m][n][r]);
}

// ---------------- PV: out = P @ V' (causal K-limit), fp32 -> d_out, XCD-affine.
__global__ __launch_bounds__(512, 1) void gemm_pv32(
    const bf16* __restrict__ Pall, const bf16* __restrict__ VTall,
    float* __restrict__ Out) {
  __shared__ bf16 smem[49152];
  const int id = blockIdx.x;
  const int bz = id & 7;
  const int w = id >> 3;
  const int bm = w & 7;
  const int bn = w >> 3;
  const long SS = 1024L * 1024;
  const bf16* A = Pall + SS * bz;
  const bf16* B = VTall + SS * bz;
  const int tid = threadIdx.x;
  const int lane = tid & 63;
  const int wid = tid >> 6;
  const int wr = wid >> 2;
  const int wc = wid & 3;
  const int lr = lane & 15;
  const int c16 = lane >> 4;
  const int bcol = bn * 256;
  const int arow = bm * 128;
  const bf16* Ag = A + (long)arow * 1024;
  const bf16* Bg = B + (long)bcol * 1024;
  bf16* sA = smem;
  bf16* sB = smem + 16384;

  f32x4 acc[4][4] = {};
  LOOP128(Ag, Bg, sA, sB, acc, (bm + 1) * 2);

  const int r0 = (lane >> 4) * 4;
  float* C = Out + SS * bz;
#pragma unroll
  for (int m = 0; m < 4; ++m)
#pragma unroll
    for (int n = 0; n < 4; ++n)
#pragma unroll
      for (int r = 0; r < 4; ++r)
        C[(long)(arow + wr * 64 + m * 16 + r0 + r) * 1024 + bcol + wc * 64 + n * 16 + lr] =
            acc[m][n][r];
}

// fp32 -> bf16 weights: wq, wk, wv transposed (64x64 LDS tiles); wo plain.
__global__ __launch_bounds__(256) void f2bw(
    const float* __restrict__ wq, const float* __restrict__ wk,
    const float* __restrict__ wv, const float* __restrict__ wo,
    bf16* __restrict__ wqTb, bf16* __restrict__ wkTb,
    bf16* __restrict__ wvTb, bf16* __restrict__ wob) {
  __shared__ float T[64][65];
  const int bid = blockIdx.x;
  const int t = threadIdx.x;
  union { bf16 h; short s; } u;

  if (bid < 768) {
    const int mat = bid >> 8;
    const int tile = bid & 255;
    const int er = tile >> 4, dc = tile & 15;
    const float* src = ((mat == 0) ? wq : (mat == 1) ? wk : wv);
    bf16* dstb = ((mat == 0) ? wqTb : (mat == 1) ? wkTb : wvTb);
    const int r = t >> 2, c = (t & 3) * 16;
    const float* s0 = src + (long)(er * 64 + r) * 1024 + dc * 64 + c;
#pragma unroll
    for (int j = 0; j < 4; ++j) {
      const float4 v = *(const float4*)(s0 + j * 4);
      T[r][c + j * 4 + 0] = v.x;
      T[r][c + j * 4 + 1] = v.y;
      T[r][c + j * 4 + 2] = v.z;
      T[r][c + j * 4 + 3] = v.w;
    }
    __syncthreads();
    const int d = t >> 2, ec = (t & 3) * 16;
    bf16* dst = dstb + (long)(dc * 64 + d) * 1024 + er * 64 + ec;
#pragma unroll
    for (int half = 0; half < 2; ++half) {
      short8 o;
#pragma unroll
      for (int j = 0; j < 8; ++j) {
        u.h = __float2bfloat16(T[ec + half * 8 + j][d]);
        o[j] = u.s;
      }
      *(short8*)(dst + half * 8) = o;
    }
    return;
  }
  const long i = (long)(bid - 768) * 2048 + t * 8;
  const float4 a = *(const float4*)&wo[i];
  const float4 b = *(const float4*)&wo[i + 4];
  const float va[8] = {a.x, a.y, a.z, a.w, b.x, b.y, b.z, b.w};
  short8 o;
#pragma unroll
  for (int j = 0; j < 8; ++j) { u.h = __float2bfloat16(va[j]); o[j] = u.s; }
  *(short8*)&wob[i] = o;
}

// In-place causal softmax, vectorized: 128 thr/row, one bf16x8 (16B) per lane.
__global__ __launch_bounds__(128) void softmax_causal(bf16* __restrict__ P) {
  const int q = blockIdx.x;
  const int b = blockIdx.y;
  bf16* row = P + ((long)b * 1024 + q) * 1024;
  const int t = threadIdx.x;
  const int n = q + 1;
  __shared__ float red[4];
  union { bf16 h; short s; } u;

  const short8 raw = *(const short8*)&row[t * 8];
  float v[8];
  float mx = -1e30f;
#pragma unroll
  for (int j = 0; j < 8; ++j) {
    const int k = t * 8 + j;
    u.s = raw[j];
    v[j] = (k < n) ? __bfloat162float(u.h) * 0.03125f : -1e30f;
    mx = fmaxf(mx, v[j]);
  }
#pragma unroll
  for (int o = 32; o > 0; o >>= 1) mx = fmaxf(mx, __shfl_xor(mx, o, 64));
  if ((t & 63) == 0) red[t >> 6] = mx;
  __syncthreads();
  mx = fmaxf(red[0], red[1]);

  float s = 0.f;
  float e[8];
#pragma unroll
  for (int j = 0; j < 8; ++j) {
    const int k = t * 8 + j;
    e[j] = (k < n) ? __expf(v[j] - mx) : 0.f;
    s += e[j];
  }
#pragma unroll
  for (int o = 32; o > 0; o >>= 1) s += __shfl_xor(s, o, 64);
  if ((t & 63) == 0) red[2 + (t >> 6)] = s;
  __syncthreads();
  s = red[2] + red[3];
  const float inv = 1.f / s;
  short8 o;
#pragma unroll
  for (int j = 0; j < 8; ++j) {
    u.h = __float2bfloat16(e[j] * inv);
    o[j] = u.s;
  }
  *(short8*)&row[t * 8] = o;
}

extern "C" void kernel_launch(void* const* d_in, const int* in_sizes, int n_in,
                              void* d_out, int out_size, void* d_ws, size_t ws_size,
                              hipStream_t stream) {
  (void)in_sizes; (void)n_in; (void)out_size; (void)ws_size;
  const float* x  = (const float*)d_in[0];
  const float* wq = (const float*)d_in[1];
  const float* wk = (const float*)d_in[2];
  const float* wv = (const float*)d_in[3];
  const float* wo = (const float*)d_in[4];
  float* out = (float*)d_out;
  bf16* ws = (bf16*)d_ws;

  const long SB = 8192L * 1024;
  const long SW = 1024L * 1024;

  bf16* xb   = ws;
  bf16* wqTb = ws + SB;
  bf16* wkTb = ws + SB + SW;
  bf16* wvTb = ws + SB + 2 * SW;
  bf16* wob  = ws + SB + 3 * SW;
  bf16* Mp   = ws + SB + 4 * SW;
  bf16* Wp   = ws + SB + 5 * SW;
  bf16* G    = ws + SB + 6 * SW;
  bf16* VT   = G + SB;
  bf16* P    = VT + SB;

  f2bw<<<dim3(1280), dim3(256), 0, stream>>>(wq, wk, wv, wo, wqTb, wkTb, wvTb, wob);
  prep2<<<dim3(4224), dim3(256), 0, stream>>>(wkTb, wqTb, wob, wvTb, Mp, Wp, x, xb);
  gemm_gv<<<dim3(256), dim3(512), 0, stream>>>(xb, Mp, Wp, G, VT);
  gemm_sc<<<dim3(160), dim3(512), 0, stream>>>(G, xb, P);
  softmax_causal<<<dim3(1024, 8), dim3(128), 0, stream>>>(P);
  gemm_pv32<<<dim3(256), dim3(512), 0, stream>>>(P, VT, out);
}

// Round 13
// 108.468 us; speedup vs baseline: 1.0412x; 1.0412x over previous
//
#include <hip/hip_runtime.h>
#include <hip/hip_bf16.h>

typedef __hip_bfloat16 bf16;
typedef __attribute__((ext_vector_type(8))) short short8;
typedef __attribute__((ext_vector_type(4))) float f32x4;

#define SBAR() asm volatile("s_barrier" ::: "memory")
#define VMCNT8() asm volatile("s_waitcnt vmcnt(8)" ::: "memory")
#define VMCNT6() asm volatile("s_waitcnt vmcnt(6)" ::: "memory")
#define VMCNT2() asm volatile("s_waitcnt vmcnt(2)" ::: "memory")
#define VMCNT0() asm volatile("s_waitcnt vmcnt(0)" ::: "memory")

__device__ __forceinline__ void gload_lds16(const bf16* g, bf16* l) {
  __builtin_amdgcn_global_load_lds(
      (const __attribute__((address_space(1))) unsigned int*)g,
      (__attribute__((address_space(3))) unsigned int*)l, 16, 0, 0);
}

// Stage one 128x64 half-tile (row-major, ld=1024) into a linear 16KB LDS slot.
// Global source col is XOR-swizzled so swizzled LDS reads are conflict-free.
__device__ __forceinline__ void stage_half(const bf16* gbase, bf16* slot, int tid) {
  const int r = tid >> 3;                    // 0..63
  const int c = ((tid & 7) ^ (r & 7)) << 3;  // swizzled 16B chunk
  gload_lds16(gbase + (long)r * 1024 + c, slot + tid * 8);
  gload_lds16(gbase + (long)(r + 64) * 1024 + c, slot + 4096 + tid * 8);
}

// Same, for 256-thread blocks (4 passes of 32 rows).
__device__ __forceinline__ void stage_tile128_t256(const bf16* gbase, bf16* slot,
                                                   int t) {
#pragma unroll
  for (int p = 0; p < 4; ++p) {
    const int r = p * 32 + (t >> 3);
    const int c = ((t & 7) ^ (r & 7)) << 3;
    gload_lds16(gbase + (long)r * 1024 + c, slot + p * 2048 + t * 8);
  }
}

// Swizzled fragment read: logical (row, 16B-chunk c16) of a [128][64] half-slot.
__device__ __forceinline__ short8 lds_frag(const bf16* slot, int row, int c16) {
  return *(const short8*)(slot + row * 64 + ((c16 ^ (row & 7)) << 3));
}

#define MFMA16(A_, B_, acc, mo, no)                                               \
  _Pragma("unroll") for (int m = 0; m < 4; ++m)                                   \
      _Pragma("unroll") for (int n = 0; n < 2; ++n)                               \
          _Pragma("unroll") for (int ks = 0; ks < 2; ++ks)                        \
              acc[m + (mo)][n + (no)] = __builtin_amdgcn_mfma_f32_16x16x32_bf16(  \
                  A_[m][ks], B_[n][ks], acc[m + (mo)][n + (no)], 0, 0, 0);

// ======== 256x256-tile 8-phase loop (round-12, equal-best).
#define LOOP256(Ag, Bg, sA, sB, acc)                                              \
  {                                                                               \
    stage_half(Ag, sA, tid);                                                      \
    stage_half(Ag + 128 * 1024, sA + 8192, tid);                                  \
    stage_half(Bg, sB, tid);                                                      \
    stage_half(Bg + 128 * 1024, sB + 8192, tid);                                  \
    stage_half(Ag + 64, sA + 16384, tid);                                         \
    stage_half(Ag + 128 * 1024 + 64, sA + 24576, tid);                            \
    stage_half(Bg + 64, sB + 16384, tid);                                         \
    VMCNT6();                                                                     \
    SBAR();                                                                       \
    const int brb = (wc & 1) * 64;                                                \
    const bf16* AsE = sA + wr * 8192;                                             \
    const bf16* AsO = sA + (2 + wr) * 8192;                                       \
    const bf16* BsE = sB + (wc >> 1) * 8192;                                      \
    const bf16* BsO = sB + (2 + (wc >> 1)) * 8192;                                \
    short8 a01[4][2], a47[4][2], b01[2][2], b23[2][2];                            \
    for (int it = 0; it < 8; ++it) {                                              \
      const int t = it * 2;                                                       \
      _Pragma("unroll") for (int m = 0; m < 4; ++m)                               \
          _Pragma("unroll") for (int ks = 0; ks < 2; ++ks)                        \
              a01[m][ks] = lds_frag(AsE, m * 16 + lr, c16 + ks * 4);              \
      _Pragma("unroll") for (int n = 0; n < 2; ++n)                               \
          _Pragma("unroll") for (int ks = 0; ks < 2; ++ks) {                      \
        b01[n][ks] = lds_frag(BsE, brb + n * 16 + lr, c16 + ks * 4);              \
        b23[n][ks] = lds_frag(BsE, brb + (n + 2) * 16 + lr, c16 + ks * 4);        \
      }                                                                           \
      stage_half(Bg + 128 * 1024 + (t + 1) * 64, sB + 24576, tid);                \
      SBAR();                                                                     \
      __builtin_amdgcn_s_setprio(1);                                              \
      MFMA16(a01, b01, acc, 0, 0);                                                \
      __builtin_amdgcn_s_setprio(0);                                              \
      SBAR();                                                                     \
      _Pragma("unroll") for (int m = 0; m < 4; ++m)                               \
          _Pragma("unroll") for (int ks = 0; ks < 2; ++ks)                        \
              a47[m][ks] = lds_frag(AsE, (m + 4) * 16 + lr, c16 + ks * 4);        \
      if (t + 2 < 16) stage_half(Bg + (t + 2) * 64, sB, tid);                     \
      SBAR();                                                                     \
      __builtin_amdgcn_s_setprio(1);                                              \
      MFMA16(a01, b23, acc, 0, 2);                                                \
      __builtin_amdgcn_s_setprio(0);                                              \
      SBAR();                                                                     \
      if (t + 2 < 16) stage_half(Ag + (t + 2) * 64, sA, tid);                     \
      SBAR();                                                                     \
      __builtin_amdgcn_s_setprio(1);                                              \
      MFMA16(a47, b23, acc, 4, 2);                                                \
      __builtin_amdgcn_s_setprio(0);                                              \
      SBAR();                                                                     \
      if (t + 2 < 16) {                                                           \
        stage_half(Ag + 128 * 1024 + (t + 2) * 64, sA + 8192, tid);               \
        VMCNT6();                                                                 \
      } else {                                                                    \
        VMCNT0();                                                                 \
      }                                                                           \
      SBAR();                                                                     \
      __builtin_amdgcn_s_setprio(1);                                              \
      MFMA16(a47, b01, acc, 4, 0);                                                \
      __builtin_amdgcn_s_setprio(0);                                              \
      SBAR();                                                                     \
      _Pragma("unroll") for (int m = 0; m < 4; ++m)                               \
          _Pragma("unroll") for (int ks = 0; ks < 2; ++ks)                        \
              a01[m][ks] = lds_frag(AsO, m * 16 + lr, c16 + ks * 4);              \
      _Pragma("unroll") for (int n = 0; n < 2; ++n)                               \
          _Pragma("unroll") for (int ks = 0; ks < 2; ++ks) {                      \
        b01[n][ks] = lds_frag(BsO, brb + n * 16 + lr, c16 + ks * 4);              \
        b23[n][ks] = lds_frag(BsO, brb + (n + 2) * 16 + lr, c16 + ks * 4);        \
      }                                                                           \
      if (t + 2 < 16)                                                             \
        stage_half(Bg + 128 * 1024 + (t + 2) * 64, sB + 8192, tid);               \
      SBAR();                                                                     \
      __builtin_amdgcn_s_setprio(1);                                              \
      MFMA16(a01, b01, acc, 0, 0);                                                \
      __builtin_amdgcn_s_setprio(0);                                              \
      SBAR();                                                                     \
      _Pragma("unroll") for (int m = 0; m < 4; ++m)                               \
          _Pragma("unroll") for (int ks = 0; ks < 2; ++ks)                        \
              a47[m][ks] = lds_frag(AsO, (m + 4) * 16 + lr, c16 + ks * 4);        \
      if (t + 3 < 16) stage_half(Bg + (t + 3) * 64, sB + 16384, tid);             \
      SBAR();                                                                     \
      __builtin_amdgcn_s_setprio(1);                                              \
      MFMA16(a01, b23, acc, 0, 2);                                                \
      __builtin_amdgcn_s_setprio(0);                                              \
      SBAR();                                                                     \
      if (t + 3 < 16) stage_half(Ag + (t + 3) * 64, sA + 16384, tid);             \
      SBAR();                                                                     \
      __builtin_amdgcn_s_setprio(1);                                              \
      MFMA16(a47, b23, acc, 4, 2);                                                \
      __builtin_amdgcn_s_setprio(0);                                              \
      SBAR();                                                                     \
      if (t + 3 < 16) {                                                           \
        stage_half(Ag + 128 * 1024 + (t + 3) * 64, sA + 24576, tid);              \
        VMCNT6();                                                                 \
      } else if (t + 2 < 16) {                                                    \
        VMCNT0();                                                                 \
      }                                                                           \
      SBAR();                                                                     \
      __builtin_amdgcn_s_setprio(1);                                              \
      MFMA16(a47, b01, acc, 4, 0);                                                \
      __builtin_amdgcn_s_setprio(0);                                              \
      SBAR();                                                                     \
    }                                                                             \
  }

// ======== 128x256-tile 2-phase loop with read-ahead (round-10/11 proven).
#define LOOP128(Ag, Bg, sA, sB, acc, NTv)                                         \
  {                                                                               \
    stage_half(Ag, sA, tid);                                                      \
    stage_half(Bg, sB, tid);                                                      \
    stage_half(Bg + 128 * 1024, sB + 8192, tid);                                  \
    stage_half(Ag + 64, sA + 8192, tid);                                          \
    VMCNT2();                                                                     \
    SBAR();                                                                       \
    const int brb = (wc & 1) * 64;                                                \
    short8 aq[4][2], b01[2][2], b23[2][2];                                        \
    _Pragma("unroll") for (int m = 0; m < 4; ++m)                                 \
        _Pragma("unroll") for (int ks = 0; ks < 2; ++ks)                          \
            aq[m][ks] = lds_frag(sA, wr * 64 + m * 16 + lr, c16 + ks * 4);        \
    _Pragma("unroll") for (int n = 0; n < 2; ++n)                                 \
        _Pragma("unroll") for (int ks = 0; ks < 2; ++ks)                          \
            b01[n][ks] = lds_frag(sB + (wc >> 1) * 8192, brb + n * 16 + lr,       \
                                  c16 + ks * 4);                                  \
    const int NT = (NTv);                                                         \
    for (int t = 0; t < NT; ++t) {                                                \
      const int rp = t & 1;                                                       \
      const int sp = rp ^ 1;                                                      \
      const bf16* Bs = sB + (rp * 2 + (wc >> 1)) * 8192;                          \
      const bf16* AsN = sA + sp * 8192;                                           \
      const bf16* BsN = sB + (sp * 2 + (wc >> 1)) * 8192;                         \
      _Pragma("unroll") for (int n = 0; n < 2; ++n)                               \
          _Pragma("unroll") for (int ks = 0; ks < 2; ++ks)                        \
              b23[n][ks] = lds_frag(Bs, brb + (n + 2) * 16 + lr, c16 + ks * 4);   \
      if (t + 1 < NT) stage_half(Bg + (t + 1) * 64, sB + sp * 2 * 8192, tid);     \
      SBAR();                                                                     \
      __builtin_amdgcn_s_setprio(1);                                              \
      _Pragma("unroll") for (int m = 0; m < 4; ++m)                               \
          _Pragma("unroll") for (int n = 0; n < 2; ++n)                           \
              _Pragma("unroll") for (int ks = 0; ks < 2; ++ks)                    \
                  acc[m][n] = __builtin_amdgcn_mfma_f32_16x16x32_bf16(            \
                      aq[m][ks], b01[n][ks], acc[m][n], 0, 0, 0);                 \
      __builtin_amdgcn_s_setprio(0);                                              \
      SBAR();                                                                     \
      if (t + 1 < NT)                                                             \
        stage_half(Bg + 128 * 1024 + (t + 1) * 64, sB + (sp * 2 + 1) * 8192, tid);\
      if (t + 2 < NT) {                                                           \
        stage_half(Ag + (t + 2) * 64, sA + rp * 8192, tid);                       \
        VMCNT2();                                                                 \
      } else if (t + 1 < NT) {                                                    \
        VMCNT0();                                                                 \
      }                                                                           \
      SBAR();                                                                     \
      __builtin_amdgcn_s_setprio(1);                                              \
      _Pragma("unroll") for (int m = 0; m < 4; ++m)                               \
          _Pragma("unroll") for (int n = 0; n < 2; ++n)                           \
              _Pragma("unroll") for (int ks = 0; ks < 2; ++ks)                    \
                  acc[m][n + 2] = __builtin_amdgcn_mfma_f32_16x16x32_bf16(        \
                      aq[m][ks], b23[n][ks], acc[m][n + 2], 0, 0, 0);             \
      __builtin_amdgcn_s_setprio(0);                                              \
      if (t + 1 < NT) {                                                           \
        _Pragma("unroll") for (int m = 0; m < 4; ++m)                             \
            _Pragma("unroll") for (int ks = 0; ks < 2; ++ks)                      \
                aq[m][ks] = lds_frag(AsN, wr * 64 + m * 16 + lr, c16 + ks * 4);   \
        _Pragma("unroll") for (int n = 0; n < 2; ++n)                             \
            _Pragma("unroll") for (int ks = 0; ks < 2; ++ks)                      \
                b01[n][ks] = lds_frag(BsN, brb + n * 16 + lr, c16 + ks * 4);      \
      }                                                                           \
      SBAR();                                                                     \
    }                                                                             \
  }

// ---------------- merged G-projection + V'-projection, XCD-affine block map.
__global__ __launch_bounds__(512, 1) void gemm_gv(
    const bf16* __restrict__ xb, const bf16* __restrict__ Mp,
    const bf16* __restrict__ Wp, bf16* __restrict__ G, bf16* __restrict__ VT) {
  __shared__ bf16 smem[65536];
  const int id = blockIdx.x;
  const int tid = threadIdx.x;
  const int lane = tid & 63;
  const int wid = tid >> 6;
  const int wr = wid >> 2;
  const int wc = wid & 3;
  const int lr = lane & 15;
  const int c16 = lane >> 4;
  const long SS = 1024L * 1024;

  const bf16 *Ag, *Bg;
  bf16* C;
  int arow, bcol;
  if (id < 128) {
    const int w = id >> 3;
    const int bm = (id & 7) + 8 * (w >> 2);
    const int bn = w & 3;
    arow = bm * 256;
    bcol = bn * 256;
    Ag = xb + (long)arow * 1024;
    Bg = Mp + (long)bcol * 1024;
    C = G;
  } else {
    const int v = id - 128;
    const int b = v & 7;
    const int gs = (v >> 3) & 3;
    const int ss = v >> 5;
    arow = gs * 256;
    bcol = ss * 256;
    Ag = Wp + (long)arow * 1024;
    Bg = xb + (long)b * SS + (long)bcol * 1024;
    C = VT + (long)b * SS;
  }
  bf16* sA = smem;
  bf16* sB = smem + 32768;

  f32x4 acc[8][4] = {};
  LOOP256(Ag, Bg, sA, sB, acc);

  const int r0 = (lane >> 4) * 4;
#pragma unroll
  for (int m = 0; m < 8; ++m)
#pragma unroll
    for (int n = 0; n < 4; ++n)
#pragma unroll
      for (int r = 0; r < 4; ++r)
        C[(long)(arow + wr * 128 + m * 16 + r0 + r) * 1024 + bcol + wc * 64 + n * 16 + lr] =
            __float2bfloat16(acc[m][n][r]);
}

// ---------------- prep2: full-K small GEMMs (blocks 0-127) overlapped with
// x fp32->bf16 conversion (blocks 128-4223).
__global__ __launch_bounds__(256, 2) void prep2(
    const bf16* __restrict__ wkT, const bf16* __restrict__ wqT,
    const bf16* __restrict__ wo, const bf16* __restrict__ wvT,
    bf16* __restrict__ Mp, bf16* __restrict__ Wp, const float* __restrict__ x,
    bf16* __restrict__ xb) {
  __shared__ bf16 smem[32768];
  const int bid = blockIdx.x;
  const int t = threadIdx.x;

  if (bid >= 128) {  // x conversion
    const long i = (long)(bid - 128) * 2048 + t * 8;
    const float4 a = *(const float4*)&x[i];
    const float4 b = *(const float4*)&x[i + 4];
    const float va[8] = {a.x, a.y, a.z, a.w, b.x, b.y, b.z, b.w};
    union { bf16 h; short s; } u;
    short8 o;
#pragma unroll
    for (int j = 0; j < 8; ++j) { u.h = __float2bfloat16(va[j]); o[j] = u.s; }
    *(short8*)&xb[i] = o;
    return;
  }

  const int mat = bid >> 6;
  const int tile = bid & 63;
  const int bm = tile >> 3, bn = tile & 7;
  const bf16* A = (mat == 0) ? wkT : wo;
  const bf16* B = (mat == 0) ? wqT : wvT;
  bf16* C = (mat == 0) ? Mp : Wp;

  const int lane = t & 63;
  const int wid = t >> 6;
  const int wr = (wid >> 1) * 64;
  const int wc = (wid & 1) * 64;
  const int lr = lane & 15;
  const int c16 = lane >> 4;
  const int arow = bm * 128;
  const int brow = bn * 128;
  const bf16* Ag = A + (long)arow * 1024;
  const bf16* Bg = B + (long)brow * 1024;
  bf16* sA = smem;
  bf16* sB = smem + 16384;

  stage_tile128_t256(Ag, sA, t);
  stage_tile128_t256(Bg, sB, t);
  stage_tile128_t256(Ag + 64, sA + 8192, t);
  stage_tile128_t256(Bg + 64, sB + 8192, t);
  VMCNT8();
  SBAR();

  f32x4 acc[4][4] = {};
  for (int tt = 0; tt < 16; ++tt) {
    const int cur = tt & 1;
    const bf16* As = sA + cur * 8192;
    const bf16* Bs = sB + cur * 8192;
    short8 a[4][2], b[4][2];
#pragma unroll
    for (int m = 0; m < 4; ++m)
#pragma unroll
      for (int ks = 0; ks < 2; ++ks)
        a[m][ks] = lds_frag(As, wr + m * 16 + lr, c16 + ks * 4);
#pragma unroll
    for (int n = 0; n < 4; ++n)
#pragma unroll
      for (int ks = 0; ks < 2; ++ks)
        b[n][ks] = lds_frag(Bs, wc + n * 16 + lr, c16 + ks * 4);
#pragma unroll
    for (int m = 0; m < 4; ++m)
#pragma unroll
      for (int n = 0; n < 4; ++n)
#pragma unroll
        for (int ks = 0; ks < 2; ++ks)
          acc[m][n] = __builtin_amdgcn_mfma_f32_16x16x32_bf16(
              a[m][ks], b[n][ks], acc[m][n], 0, 0, 0);
    SBAR();
    if (tt + 2 < 16) {
      stage_tile128_t256(Ag + (tt + 2) * 64, sA + cur * 8192, t);
      stage_tile128_t256(Bg + (tt + 2) * 64, sB + cur * 8192, t);
      VMCNT8();
    } else if (tt + 1 < 16) {
      VMCNT0();
    }
    SBAR();
  }

#pragma unroll
  for (int m = 0; m < 4; ++m)
#pragma unroll
    for (int n = 0; n < 4; ++n)
#pragma unroll
      for (int r = 0; r < 4; ++r) {
        const int row = arow + wr + m * 16 + (lane >> 4) * 4 + r;
        const int col = brow + wc + n * 16 + lr;
        C[(long)row * 1024 + col] = __float2bfloat16(acc[m][n][r]);
      }
}

// ---------------- scores -> unnormalized P~ = exp(s/32) with causal mask,
// plus deterministic per-row partial sums part_l[bz][bm][bn][128].
__global__ __launch_bounds__(512, 1) void gemm_sc(
    const bf16* __restrict__ Gall, const bf16* __restrict__ xball,
    bf16* __restrict__ Pall, float* __restrict__ part_l) {
  __shared__ bf16 smem[49152];
  const int id = blockIdx.x;
  const int bz = id & 7;
  int rr = id >> 3, bm = 0;
  while (rr >= bm / 2 + 1) { rr -= bm / 2 + 1; ++bm; }
  const int bn = rr;
  const long SS = 1024L * 1024;
  const bf16* A = Gall + SS * bz;
  const bf16* B = xball + SS * bz;
  const int tid = threadIdx.x;
  const int lane = tid & 63;
  const int wid = tid >> 6;
  const int wr = wid >> 2;
  const int wc = wid & 3;
  const int lr = lane & 15;
  const int c16 = lane >> 4;
  const int bcol = bn * 256;
  const int arow = bm * 128;
  const bf16* Ag = A + (long)arow * 1024;
  const bf16* Bg = B + (long)bcol * 1024;
  bf16* sA = smem;
  bf16* sB = smem + 16384;

  f32x4 acc[4][4] = {};
  LOOP128(Ag, Bg, sA, sB, acc, 16);

  // epilogue: exp + causal mask + store + per-row partial sums (deterministic)
  const int r0 = (lane >> 4) * 4;
  bf16* C = Pall + SS * bz;
  float rsum[4][4];
#pragma unroll
  for (int m = 0; m < 4; ++m)
#pragma unroll
    for (int r = 0; r < 4; ++r) rsum[m][r] = 0.f;
#pragma unroll
  for (int m = 0; m < 4; ++m)
#pragma unroll
    for (int n = 0; n < 4; ++n)
#pragma unroll
      for (int r = 0; r < 4; ++r) {
        const int row = arow + wr * 64 + m * 16 + r0 + r;
        const int col = bcol + wc * 64 + n * 16 + lr;
        const float e = (col <= row) ? __expf(acc[m][n][r] * 0.03125f) : 0.f;
        C[(long)row * 1024 + col] = __float2bfloat16(e);
        rsum[m][r] += e;
      }
  // reduce over the 16 lanes (lr) of each quarter-wave
#pragma unroll
  for (int m = 0; m < 4; ++m)
#pragma unroll
    for (int r = 0; r < 4; ++r) {
#pragma unroll
      for (int o = 1; o < 16; o <<= 1)
        rsum[m][r] += __shfl_xor(rsum[m][r], o, 64);
    }
  float* wsum = (float*)smem;  // [4][128]; LDS free after loop's final barrier
  if (lr == 0) {
#pragma unroll
    for (int m = 0; m < 4; ++m)
#pragma unroll
      for (int r = 0; r < 4; ++r)
        wsum[wc * 128 + wr * 64 + m * 16 + (lane >> 4) * 4 + r] = rsum[m][r];
  }
  __syncthreads();
  if (tid < 128) {
    const float l = (wsum[tid] + wsum[128 + tid]) + (wsum[256 + tid] + wsum[384 + tid]);
    part_l[(((long)bz * 8 + bm) * 4 + bn) * 128 + tid] = l;
  }
}

// ---------------- PV: out = (P~ @ V') * linv (causal K-limit), fp32 -> d_out.
__global__ __launch_bounds__(512, 1) void gemm_pv32(
    const bf16* __restrict__ Pall, const bf16* __restrict__ VTall,
    const float* __restrict__ part_l, float* __restrict__ Out) {
  __shared__ bf16 smem[49152];
  const int id = blockIdx.x;
  const int bz = id & 7;
  const int w = id >> 3;
  const int bm = w & 7;
  const int bn = w >> 3;
  const long SS = 1024L * 1024;
  const bf16* A = Pall + SS * bz;
  const bf16* B = VTall + SS * bz;
  const int tid = threadIdx.x;
  const int lane = tid & 63;
  const int wid = tid >> 6;
  const int wr = wid >> 2;
  const int wc = wid & 3;
  const int lr = lane & 15;
  const int c16 = lane >> 4;
  const int bcol = bn * 256;
  const int arow = bm * 128;
  const bf16* Ag = A + (long)arow * 1024;
  const bf16* Bg = B + (long)bcol * 1024;
  bf16* sA = smem;
  bf16* sB = smem + 16384;

  f32x4 acc[4][4] = {};
  LOOP128(Ag, Bg, sA, sB, acc, (bm + 1) * 2);

  // build linv[128] for this row strip (deterministic fixed-order sum)
  float* linv = (float*)smem;  // LDS free after loop's final barrier
  if (tid < 128) {
    const int nb = bm / 2 + 1;
    float l = 0.f;
    for (int j = 0; j < nb; ++j)
      l += part_l[(((long)bz * 8 + bm) * 4 + j) * 128 + tid];
    linv[tid] = 1.f / l;
  }
  __syncthreads();

  const int r0 = (lane >> 4) * 4;
  float* C = Out + SS * bz;
#pragma unroll
  for (int m = 0; m < 4; ++m)
#pragma unroll
    for (int r = 0; r < 4; ++r) {
      const int rl = wr * 64 + m * 16 + r0 + r;
      const float s = linv[rl];
#pragma unroll
      for (int n = 0; n < 4; ++n)
        C[(long)(arow + rl) * 1024 + bcol + wc * 64 + n * 16 + lr] =
            acc[m][n][r] * s;
    }
}

// fp32 -> bf16 weights: wq, wk, wv transposed (64x64 LDS tiles); wo plain.
__global__ __launch_bounds__(256) void f2bw(
    const float* __restrict__ wq, const float* __restrict__ wk,
    const float* __restrict__ wv, const float* __restrict__ wo,
    bf16* __restrict__ wqTb, bf16* __restrict__ wkTb,
    bf16* __restrict__ wvTb, bf16* __restrict__ wob) {
  __shared__ float T[64][65];
  const int bid = blockIdx.x;
  const int t = threadIdx.x;
  union { bf16 h; short s; } u;

  if (bid < 768) {
    const int mat = bid >> 8;
    const int tile = bid & 255;
    const int er = tile >> 4, dc = tile & 15;
    const float* src = ((mat == 0) ? wq : (mat == 1) ? wk : wv);
    bf16* dstb = ((mat == 0) ? wqTb : (mat == 1) ? wkTb : wvTb);
    const int r = t >> 2, c = (t & 3) * 16;
    const float* s0 = src + (long)(er * 64 + r) * 1024 + dc * 64 + c;
#pragma unroll
    for (int j = 0; j < 4; ++j) {
      const float4 v = *(const float4*)(s0 + j * 4);
      T[r][c + j * 4 + 0] = v.x;
      T[r][c + j * 4 + 1] = v.y;
      T[r][c + j * 4 + 2] = v.z;
      T[r][c + j * 4 + 3] = v.w;
    }
    __syncthreads();
    const int d = t >> 2, ec = (t & 3) * 16;
    bf16* dst = dstb + (long)(dc * 64 + d) * 1024 + er * 64 + ec;
#pragma unroll
    for (int half = 0; half < 2; ++half) {
      short8 o;
#pragma unroll
      for (int j = 0; j < 8; ++j) {
        u.h = __float2bfloat16(T[ec + half * 8 + j][d]);
        o[j] = u.s;
      }
      *(short8*)(dst + half * 8) = o;
    }
    return;
  }
  const long i = (long)(bid - 768) * 2048 + t * 8;
  const float4 a = *(const float4*)&wo[i];
  const float4 b = *(const float4*)&wo[i + 4];
  const float va[8] = {a.x, a.y, a.z, a.w, b.x, b.y, b.z, b.w};
  short8 o;
#pragma unroll
  for (int j = 0; j < 8; ++j) { u.h = __float2bfloat16(va[j]); o[j] = u.s; }
  *(short8*)&wob[i] = o;
}

extern "C" void kernel_launch(void* const* d_in, const int* in_sizes, int n_in,
                              void* d_out, int out_size, void* d_ws, size_t ws_size,
                              hipStream_t stream) {
  (void)in_sizes; (void)n_in; (void)out_size; (void)ws_size;
  const float* x  = (const float*)d_in[0];
  const float* wq = (const float*)d_in[1];
  const float* wk = (const float*)d_in[2];
  const float* wv = (const float*)d_in[3];
  const float* wo = (const float*)d_in[4];
  float* out = (float*)d_out;
  bf16* ws = (bf16*)d_ws;

  const long SB = 8192L * 1024;
  const long SW = 1024L * 1024;

  bf16* xb   = ws;                    // [8][s][d]
  bf16* wqTb = ws + SB;               // wq^T [d][e]
  bf16* wkTb = ws + SB + SW;          // wk^T [d][e]
  bf16* wvTb = ws + SB + 2 * SW;      // wv^T [d][e]
  bf16* wob  = ws + SB + 3 * SW;      // wo   [g][e]
  bf16* Mp   = ws + SB + 4 * SW;      // M' = wq^T wk
  bf16* Wp   = ws + SB + 5 * SW;      // W' = wo wv
  bf16* G    = ws + SB + 6 * SW;      // [8192][1024]
  bf16* VT   = G + SB;                // V'^T [8][g][s]
  bf16* P    = VT + SB;               // unnormalized P~ (exp of scaled scores)
  float* part_l = (float*)(P + SB);   // [8][8][4][128] row partial sums

  f2bw<<<dim3(1280), dim3(256), 0, stream>>>(wq, wk, wv, wo, wqTb, wkTb, wvTb, wob);
  prep2<<<dim3(4224), dim3(256), 0, stream>>>(wkTb, wqTb, wob, wvTb, Mp, Wp, x, xb);
  gemm_gv<<<dim3(256), dim3(512), 0, stream>>>(xb, Mp, Wp, G, VT);
  // scores + exp + causal mask + partial row sums (softmax kernel eliminated)
  gemm_sc<<<dim3(160), dim3(512), 0, stream>>>(G, xb, P, part_l);
  // out = (P~ @ V') / l, fp32 straight to d_out
  gemm_pv32<<<dim3(256), dim3(512), 0, stream>>>(P, VT, part_l, out);
}

// Round 14
// 104.695 us; speedup vs baseline: 1.0787x; 1.0360x over previous
//
#include <hip/hip_runtime.h>
#include <hip/hip_bf16.h>

typedef __hip_bfloat16 bf16;
typedef __attribute__((ext_vector_type(8))) short short8;
typedef __attribute__((ext_vector_type(4))) float f32x4;

#define SBAR() asm volatile("s_barrier" ::: "memory")
#define VMCNT8() asm volatile("s_waitcnt vmcnt(8)" ::: "memory")
#define VMCNT6() asm volatile("s_waitcnt vmcnt(6)" ::: "memory")
#define VMCNT0() asm volatile("s_waitcnt vmcnt(0)" ::: "memory")

__device__ __forceinline__ void gload_lds16(const bf16* g, bf16* l) {
  __builtin_amdgcn_global_load_lds(
      (const __attribute__((address_space(1))) unsigned int*)g,
      (__attribute__((address_space(3))) unsigned int*)l, 16, 0, 0);
}

// Stage one 128x64 half-tile (row-major, ld=1024) into a linear 16KB LDS slot.
// Global source col is XOR-swizzled so swizzled LDS reads are conflict-free.
__device__ __forceinline__ void stage_half(const bf16* gbase, bf16* slot, int tid) {
  const int r = tid >> 3;                    // 0..63
  const int c = ((tid & 7) ^ (r & 7)) << 3;  // swizzled 16B chunk
  gload_lds16(gbase + (long)r * 1024 + c, slot + tid * 8);
  gload_lds16(gbase + (long)(r + 64) * 1024 + c, slot + 4096 + tid * 8);
}

// Same, for 256-thread blocks (4 passes of 32 rows).
__device__ __forceinline__ void stage_tile128_t256(const bf16* gbase, bf16* slot,
                                                   int t) {
#pragma unroll
  for (int p = 0; p < 4; ++p) {
    const int r = p * 32 + (t >> 3);
    const int c = ((t & 7) ^ (r & 7)) << 3;
    gload_lds16(gbase + (long)r * 1024 + c, slot + p * 2048 + t * 8);
  }
}

// Swizzled fragment read: logical (row, 16B-chunk c16) of a [128][64] half-slot.
__device__ __forceinline__ short8 lds_frag(const bf16* slot, int row, int c16) {
  return *(const short8*)(slot + row * 64 + ((c16 ^ (row & 7)) << 3));
}

#define MFMA16(A_, B_, acc, mo, no)                                               \
  _Pragma("unroll") for (int m = 0; m < 4; ++m)                                   \
      _Pragma("unroll") for (int n = 0; n < 2; ++n)                               \
          _Pragma("unroll") for (int ks = 0; ks < 2; ++ks)                        \
              acc[m + (mo)][n + (no)] = __builtin_amdgcn_mfma_f32_16x16x32_bf16(  \
                  A_[m][ks], B_[n][ks], acc[m + (mo)][n + (no)], 0, 0, 0);

// ======== 256x256-tile 2-barrier loop: reads+MFMA fused in one region
// (compiler interleaves ds_read/MFMA with counted lgkmcnt); one full-tile
// stage per K-tile with counted VMCNT8. Slots: sA/sB 2 full K-tiles
// (16384 elems each, halves at +0/+8192).
#define LOOP256(Ag, Bg, sA, sB, acc)                                              \
  {                                                                               \
    stage_half(Ag, sA, tid);                                                      \
    stage_half(Ag + 128 * 1024, sA + 8192, tid);                                  \
    stage_half(Bg, sB, tid);                                                      \
    stage_half(Bg + 128 * 1024, sB + 8192, tid);                                  \
    stage_half(Ag + 64, sA + 16384, tid);                                         \
    stage_half(Ag + 128 * 1024 + 64, sA + 24576, tid);                            \
    stage_half(Bg + 64, sB + 16384, tid);                                         \
    stage_half(Bg + 128 * 1024 + 64, sB + 24576, tid);                            \
    VMCNT8();                                                                     \
    SBAR();                                                                       \
    const int brb = (wc & 1) * 64;                                                \
    for (int t = 0; t < 16; ++t) {                                                \
      const int cur = t & 1;                                                      \
      const bf16* As = sA + cur * 16384 + wr * 8192;                              \
      const bf16* Bs = sB + cur * 16384 + (wc >> 1) * 8192;                       \
      short8 a01[4][2], a47[4][2], b01[2][2], b23[2][2];                          \
      _Pragma("unroll") for (int m = 0; m < 4; ++m)                               \
          _Pragma("unroll") for (int ks = 0; ks < 2; ++ks) {                      \
        a01[m][ks] = lds_frag(As, m * 16 + lr, c16 + ks * 4);                     \
        a47[m][ks] = lds_frag(As, (m + 4) * 16 + lr, c16 + ks * 4);               \
      }                                                                           \
      _Pragma("unroll") for (int n = 0; n < 2; ++n)                               \
          _Pragma("unroll") for (int ks = 0; ks < 2; ++ks) {                      \
        b01[n][ks] = lds_frag(Bs, brb + n * 16 + lr, c16 + ks * 4);               \
        b23[n][ks] = lds_frag(Bs, brb + (n + 2) * 16 + lr, c16 + ks * 4);         \
      }                                                                           \
      __builtin_amdgcn_s_setprio(1);                                              \
      MFMA16(a01, b01, acc, 0, 0);                                                \
      MFMA16(a01, b23, acc, 0, 2);                                                \
      MFMA16(a47, b01, acc, 4, 0);                                                \
      MFMA16(a47, b23, acc, 4, 2);                                                \
      __builtin_amdgcn_s_setprio(0);                                              \
      SBAR(); /* all waves drained their reads of slot cur (via MFMA lgkm) */     \
      if (t + 2 < 16) {                                                           \
        stage_half(Ag + (t + 2) * 64, sA + cur * 16384, tid);                     \
        stage_half(Ag + 128 * 1024 + (t + 2) * 64, sA + cur * 16384 + 8192, tid); \
        stage_half(Bg + (t + 2) * 64, sB + cur * 16384, tid);                     \
        stage_half(Bg + 128 * 1024 + (t + 2) * 64, sB + cur * 16384 + 8192, tid); \
        VMCNT8(); /* tile t+1 landed; t+2 stays in flight */                      \
      } else if (t + 1 < 16) {                                                    \
        VMCNT0();                                                                 \
      }                                                                           \
      SBAR();                                                                     \
    }                                                                             \
  }

// ======== 128x256-tile 2-barrier loop (same transform; 6 loads/K-tile).
// Slots: sA 2 x 8192 elems; sB 2 x 16384 elems (halves at +0/+8192).
#define LOOP128(Ag, Bg, sA, sB, acc, NTv)                                         \
  {                                                                               \
    stage_half(Ag, sA, tid);                                                      \
    stage_half(Bg, sB, tid);                                                      \
    stage_half(Bg + 128 * 1024, sB + 8192, tid);                                  \
    stage_half(Ag + 64, sA + 8192, tid);                                          \
    stage_half(Bg + 64, sB + 16384, tid);                                         \
    stage_half(Bg + 128 * 1024 + 64, sB + 24576, tid);                            \
    VMCNT6();                                                                     \
    SBAR();                                                                       \
    const int brb = (wc & 1) * 64;                                                \
    const int NT = (NTv);                                                         \
    for (int t = 0; t < NT; ++t) {                                                \
      const int cur = t & 1;                                                      \
      const bf16* As = sA + cur * 8192;                                           \
      const bf16* Bs = sB + cur * 16384 + (wc >> 1) * 8192;                       \
      short8 aq[4][2], b01[2][2], b23[2][2];                                      \
      _Pragma("unroll") for (int m = 0; m < 4; ++m)                               \
          _Pragma("unroll") for (int ks = 0; ks < 2; ++ks)                        \
              aq[m][ks] = lds_frag(As, wr * 64 + m * 16 + lr, c16 + ks * 4);      \
      _Pragma("unroll") for (int n = 0; n < 2; ++n)                               \
          _Pragma("unroll") for (int ks = 0; ks < 2; ++ks) {                      \
        b01[n][ks] = lds_frag(Bs, brb + n * 16 + lr, c16 + ks * 4);               \
        b23[n][ks] = lds_frag(Bs, brb + (n + 2) * 16 + lr, c16 + ks * 4);         \
      }                                                                           \
      __builtin_amdgcn_s_setprio(1);                                              \
      MFMA16(aq, b01, acc, 0, 0);                                                 \
      MFMA16(aq, b23, acc, 0, 2);                                                 \
      __builtin_amdgcn_s_setprio(0);                                              \
      SBAR();                                                                     \
      if (t + 2 < NT) {                                                           \
        stage_half(Ag + (t + 2) * 64, sA + cur * 8192, tid);                      \
        stage_half(Bg + (t + 2) * 64, sB + cur * 16384, tid);                     \
        stage_half(Bg + 128 * 1024 + (t + 2) * 64, sB + cur * 16384 + 8192, tid); \
        VMCNT6();                                                                 \
      } else if (t + 1 < NT) {                                                    \
        VMCNT0();                                                                 \
      }                                                                           \
      SBAR();                                                                     \
    }                                                                             \
  }

// ---------------- merged G-projection + V'-projection, XCD-affine block map.
__global__ __launch_bounds__(512, 1) void gemm_gv(
    const bf16* __restrict__ xb, const bf16* __restrict__ Mp,
    const bf16* __restrict__ Wp, bf16* __restrict__ G, bf16* __restrict__ VT) {
  __shared__ bf16 smem[65536];
  const int id = blockIdx.x;
  const int tid = threadIdx.x;
  const int lane = tid & 63;
  const int wid = tid >> 6;
  const int wr = wid >> 2;
  const int wc = wid & 3;
  const int lr = lane & 15;
  const int c16 = lane >> 4;
  const long SS = 1024L * 1024;

  const bf16 *Ag, *Bg;
  bf16* C;
  int arow, bcol;
  if (id < 128) {
    const int w = id >> 3;
    const int bm = (id & 7) + 8 * (w >> 2);
    const int bn = w & 3;
    arow = bm * 256;
    bcol = bn * 256;
    Ag = xb + (long)arow * 1024;
    Bg = Mp + (long)bcol * 1024;
    C = G;
  } else {
    const int v = id - 128;
    const int b = v & 7;
    const int gs = (v >> 3) & 3;
    const int ss = v >> 5;
    arow = gs * 256;
    bcol = ss * 256;
    Ag = Wp + (long)arow * 1024;
    Bg = xb + (long)b * SS + (long)bcol * 1024;
    C = VT + (long)b * SS;
  }
  bf16* sA = smem;
  bf16* sB = smem + 32768;

  f32x4 acc[8][4] = {};
  LOOP256(Ag, Bg, sA, sB, acc);

  const int r0 = (lane >> 4) * 4;
#pragma unroll
  for (int m = 0; m < 8; ++m)
#pragma unroll
    for (int n = 0; n < 4; ++n)
#pragma unroll
      for (int r = 0; r < 4; ++r)
        C[(long)(arow + wr * 128 + m * 16 + r0 + r) * 1024 + bcol + wc * 64 + n * 16 + lr] =
            __float2bfloat16(acc[m][n][r]);
}

// ---------------- prep2: full-K small GEMMs (blocks 0-127) overlapped with
// x fp32->bf16 conversion (blocks 128-4223).
__global__ __launch_bounds__(256, 2) void prep2(
    const bf16* __restrict__ wkT, const bf16* __restrict__ wqT,
    const bf16* __restrict__ wo, const bf16* __restrict__ wvT,
    bf16* __restrict__ Mp, bf16* __restrict__ Wp, const float* __restrict__ x,
    bf16* __restrict__ xb) {
  __shared__ bf16 smem[32768];
  const int bid = blockIdx.x;
  const int t = threadIdx.x;

  if (bid >= 128) {  // x conversion
    const long i = (long)(bid - 128) * 2048 + t * 8;
    const float4 a = *(const float4*)&x[i];
    const float4 b = *(const float4*)&x[i + 4];
    const float va[8] = {a.x, a.y, a.z, a.w, b.x, b.y, b.z, b.w};
    union { bf16 h; short s; } u;
    short8 o;
#pragma unroll
    for (int j = 0; j < 8; ++j) { u.h = __float2bfloat16(va[j]); o[j] = u.s; }
    *(short8*)&xb[i] = o;
    return;
  }

  const int mat = bid >> 6;
  const int tile = bid & 63;
  const int bm = tile >> 3, bn = tile & 7;
  const bf16* A = (mat == 0) ? wkT : wo;
  const bf16* B = (mat == 0) ? wqT : wvT;
  bf16* C = (mat == 0) ? Mp : Wp;

  const int lane = t & 63;
  const int wid = t >> 6;
  const int wr = (wid >> 1) * 64;
  const int wc = (wid & 1) * 64;
  const int lr = lane & 15;
  const int c16 = lane >> 4;
  const int arow = bm * 128;
  const int brow = bn * 128;
  const bf16* Ag = A + (long)arow * 1024;
  const bf16* Bg = B + (long)brow * 1024;
  bf16* sA = smem;
  bf16* sB = smem + 16384;

  stage_tile128_t256(Ag, sA, t);
  stage_tile128_t256(Bg, sB, t);
  stage_tile128_t256(Ag + 64, sA + 8192, t);
  stage_tile128_t256(Bg + 64, sB + 8192, t);
  VMCNT8();
  SBAR();

  f32x4 acc[4][4] = {};
  for (int tt = 0; tt < 16; ++tt) {
    const int cur = tt & 1;
    const bf16* As = sA + cur * 8192;
    const bf16* Bs = sB + cur * 8192;
    short8 a[4][2], b[4][2];
#pragma unroll
    for (int m = 0; m < 4; ++m)
#pragma unroll
      for (int ks = 0; ks < 2; ++ks)
        a[m][ks] = lds_frag(As, wr + m * 16 + lr, c16 + ks * 4);
#pragma unroll
    for (int n = 0; n < 4; ++n)
#pragma unroll
      for (int ks = 0; ks < 2; ++ks)
        b[n][ks] = lds_frag(Bs, wc + n * 16 + lr, c16 + ks * 4);
#pragma unroll
    for (int m = 0; m < 4; ++m)
#pragma unroll
      for (int n = 0; n < 4; ++n)
#pragma unroll
        for (int ks = 0; ks < 2; ++ks)
          acc[m][n] = __builtin_amdgcn_mfma_f32_16x16x32_bf16(
              a[m][ks], b[n][ks], acc[m][n], 0, 0, 0);
    SBAR();
    if (tt + 2 < 16) {
      stage_tile128_t256(Ag + (tt + 2) * 64, sA + cur * 8192, t);
      stage_tile128_t256(Bg + (tt + 2) * 64, sB + cur * 8192, t);
      VMCNT8();
    } else if (tt + 1 < 16) {
      VMCNT0();
    }
    SBAR();
  }

#pragma unroll
  for (int m = 0; m < 4; ++m)
#pragma unroll
    for (int n = 0; n < 4; ++n)
#pragma unroll
      for (int r = 0; r < 4; ++r) {
        const int row = arow + wr + m * 16 + (lane >> 4) * 4 + r;
        const int col = brow + wc + n * 16 + lr;
        C[(long)row * 1024 + col] = __float2bfloat16(acc[m][n][r]);
      }
}

// ---------------- scores -> unnormalized P~ = exp(s/32) with causal mask,
// plus deterministic per-row partial sums part_l[bz][bm][bn][128].
__global__ __launch_bounds__(512, 1) void gemm_sc(
    const bf16* __restrict__ Gall, const bf16* __restrict__ xball,
    bf16* __restrict__ Pall, float* __restrict__ part_l) {
  __shared__ bf16 smem[49152];
  const int id = blockIdx.x;
  const int bz = id & 7;
  int rr = id >> 3, bm = 0;
  while (rr >= bm / 2 + 1) { rr -= bm / 2 + 1; ++bm; }
  const int bn = rr;
  const long SS = 1024L * 1024;
  const bf16* A = Gall + SS * bz;
  const bf16* B = xball + SS * bz;
  const int tid = threadIdx.x;
  const int lane = tid & 63;
  const int wid = tid >> 6;
  const int wr = wid >> 2;
  const int wc = wid & 3;
  const int lr = lane & 15;
  const int c16 = lane >> 4;
  const int bcol = bn * 256;
  const int arow = bm * 128;
  const bf16* Ag = A + (long)arow * 1024;
  const bf16* Bg = B + (long)bcol * 1024;
  bf16* sA = smem;
  bf16* sB = smem + 16384;

  f32x4 acc[4][4] = {};
  LOOP128(Ag, Bg, sA, sB, acc, 16);

  // epilogue: exp + causal mask + store + per-row partial sums (deterministic)
  const int r0 = (lane >> 4) * 4;
  bf16* C = Pall + SS * bz;
  float rsum[4][4];
#pragma unroll
  for (int m = 0; m < 4; ++m)
#pragma unroll
    for (int r = 0; r < 4; ++r) rsum[m][r] = 0.f;
#pragma unroll
  for (int m = 0; m < 4; ++m)
#pragma unroll
    for (int n = 0; n < 4; ++n)
#pragma unroll
      for (int r = 0; r < 4; ++r) {
        const int row = arow + wr * 64 + m * 16 + r0 + r;
        const int col = bcol + wc * 64 + n * 16 + lr;
        const float e = (col <= row) ? __expf(acc[m][n][r] * 0.03125f) : 0.f;
        C[(long)row * 1024 + col] = __float2bfloat16(e);
        rsum[m][r] += e;
      }
#pragma unroll
  for (int m = 0; m < 4; ++m)
#pragma unroll
    for (int r = 0; r < 4; ++r) {
#pragma unroll
      for (int o = 1; o < 16; o <<= 1)
        rsum[m][r] += __shfl_xor(rsum[m][r], o, 64);
    }
  float* wsum = (float*)smem;  // LDS free after loop's final barrier
  if (lr == 0) {
#pragma unroll
    for (int m = 0; m < 4; ++m)
#pragma unroll
      for (int r = 0; r < 4; ++r)
        wsum[wc * 128 + wr * 64 + m * 16 + (lane >> 4) * 4 + r] = rsum[m][r];
  }
  __syncthreads();
  if (tid < 128) {
    const float l = (wsum[tid] + wsum[128 + tid]) + (wsum[256 + tid] + wsum[384 + tid]);
    part_l[(((long)bz * 8 + bm) * 4 + bn) * 128 + tid] = l;
  }
}

// ---------------- PV: out = (P~ @ V') * linv (causal K-limit), fp32 -> d_out.
__global__ __launch_bounds__(512, 1) void gemm_pv32(
    const bf16* __restrict__ Pall, const bf16* __restrict__ VTall,
    const float* __restrict__ part_l, float* __restrict__ Out) {
  __shared__ bf16 smem[49152];
  const int id = blockIdx.x;
  const int bz = id & 7;
  const int w = id >> 3;
  const int bm = w & 7;
  const int bn = w >> 3;
  const long SS = 1024L * 1024;
  const bf16* A = Pall + SS * bz;
  const bf16* B = VTall + SS * bz;
  const int tid = threadIdx.x;
  const int lane = tid & 63;
  const int wid = tid >> 6;
  const int wr = wid >> 2;
  const int wc = wid & 3;
  const int lr = lane & 15;
  const int c16 = lane >> 4;
  const int bcol = bn * 256;
  const int arow = bm * 128;
  const bf16* Ag = A + (long)arow * 1024;
  const bf16* Bg = B + (long)bcol * 1024;
  bf16* sA = smem;
  bf16* sB = smem + 16384;

  f32x4 acc[4][4] = {};
  LOOP128(Ag, Bg, sA, sB, acc, (bm + 1) * 2);

  float* linv = (float*)smem;  // LDS free after loop's final barrier
  if (tid < 128) {
    const int nb = bm / 2 + 1;
    float l = 0.f;
    for (int j = 0; j < nb; ++j)
      l += part_l[(((long)bz * 8 + bm) * 4 + j) * 128 + tid];
    linv[tid] = 1.f / l;
  }
  __syncthreads();

  const int r0 = (lane >> 4) * 4;
  float* C = Out + SS * bz;
#pragma unroll
  for (int m = 0; m < 4; ++m)
#pragma unroll
    for (int r = 0; r < 4; ++r) {
      const int rl = wr * 64 + m * 16 + r0 + r;
      const float s = linv[rl];
#pragma unroll
      for (int n = 0; n < 4; ++n)
        C[(long)(arow + rl) * 1024 + bcol + wc * 64 + n * 16 + lr] =
            acc[m][n][r] * s;
    }
}

// fp32 -> bf16 weights: wq, wk, wv transposed (64x64 LDS tiles); wo plain.
__global__ __launch_bounds__(256) void f2bw(
    const float* __restrict__ wq, const float* __restrict__ wk,
    const float* __restrict__ wv, const float* __restrict__ wo,
    bf16* __restrict__ wqTb, bf16* __restrict__ wkTb,
    bf16* __restrict__ wvTb, bf16* __restrict__ wob) {
  __shared__ float T[64][65];
  const int bid = blockIdx.x;
  const int t = threadIdx.x;
  union { bf16 h; short s; } u;

  if (bid < 768) {
    const int mat = bid >> 8;
    const int tile = bid & 255;
    const int er = tile >> 4, dc = tile & 15;
    const float* src = ((mat == 0) ? wq : (mat == 1) ? wk : wv);
    bf16* dstb = ((mat == 0) ? wqTb : (mat == 1) ? wkTb : wvTb);
    const int r = t >> 2, c = (t & 3) * 16;
    const float* s0 = src + (long)(er * 64 + r) * 1024 + dc * 64 + c;
#pragma unroll
    for (int j = 0; j < 4; ++j) {
      const float4 v = *(const float4*)(s0 + j * 4);
      T[r][c + j * 4 + 0] = v.x;
      T[r][c + j * 4 + 1] = v.y;
      T[r][c + j * 4 + 2] = v.z;
      T[r][c + j * 4 + 3] = v.w;
    }
    __syncthreads();
    const int d = t >> 2, ec = (t & 3) * 16;
    bf16* dst = dstb + (long)(dc * 64 + d) * 1024 + er * 64 + ec;
#pragma unroll
    for (int half = 0; half < 2; ++half) {
      short8 o;
#pragma unroll
      for (int j = 0; j < 8; ++j) {
        u.h = __float2bfloat16(T[ec + half * 8 + j][d]);
        o[j] = u.s;
      }
      *(short8*)(dst + half * 8) = o;
    }
    return;
  }
  const long i = (long)(bid - 768) * 2048 + t * 8;
  const float4 a = *(const float4*)&wo[i];
  const float4 b = *(const float4*)&wo[i + 4];
  const float va[8] = {a.x, a.y, a.z, a.w, b.x, b.y, b.z, b.w};
  short8 o;
#pragma unroll
  for (int j = 0; j < 8; ++j) { u.h = __float2bfloat16(va[j]); o[j] = u.s; }
  *(short8*)&wob[i] = o;
}

extern "C" void kernel_launch(void* const* d_in, const int* in_sizes, int n_in,
                              void* d_out, int out_size, void* d_ws, size_t ws_size,
                              hipStream_t stream) {
  (void)in_sizes; (void)n_in; (void)out_size; (void)ws_size;
  const float* x  = (const float*)d_in[0];
  const float* wq = (const float*)d_in[1];
  const float* wk = (const float*)d_in[2];
  const float* wv = (const float*)d_in[3];
  const float* wo = (const float*)d_in[4];
  float* out = (float*)d_out;
  bf16* ws = (bf16*)d_ws;

  const long SB = 8192L * 1024;
  const long SW = 1024L * 1024;

  bf16* xb   = ws;                    // [8][s][d]
  bf16* wqTb = ws + SB;               // wq^T [d][e]
  bf16* wkTb = ws + SB + SW;          // wk^T [d][e]
  bf16* wvTb = ws + SB + 2 * SW;      // wv^T [d][e]
  bf16* wob  = ws + SB + 3 * SW;      // wo   [g][e]
  bf16* Mp   = ws + SB + 4 * SW;      // M' = wq^T wk
  bf16* Wp   = ws + SB + 5 * SW;      // W' = wo wv
  bf16* G    = ws + SB + 6 * SW;      // [8192][1024]
  bf16* VT   = G + SB;                // V'^T [8][g][s]
  bf16* P    = VT + SB;               // unnormalized P~
  float* part_l = (float*)(P + SB);   // [8][8][4][128] row partial sums

  f2bw<<<dim3(1280), dim3(256), 0, stream>>>(wq, wk, wv, wo, wqTb, wkTb, wvTb, wob);
  prep2<<<dim3(4224), dim3(256), 0, stream>>>(wkTb, wqTb, wob, wvTb, Mp, Wp, x, xb);
  gemm_gv<<<dim3(256), dim3(512), 0, stream>>>(xb, Mp, Wp, G, VT);
  gemm_sc<<<dim3(160), dim3(512), 0, stream>>>(G, xb, P, part_l);
  gemm_pv32<<<dim3(256), dim3(512), 0, stream>>>(P, VT, part_l, out);
}

// Round 15
// 98.716 us; speedup vs baseline: 1.1441x; 1.0606x over previous
//
#include <hip/hip_runtime.h>
#include <hip/hip_bf16.h>

typedef __hip_bfloat16 bf16;
typedef __attribute__((ext_vector_type(8))) short short8;
typedef __attribute__((ext_vector_type(4))) float f32x4;

#define SBAR() asm volatile("s_barrier" ::: "memory")
#define VMCNT8() asm volatile("s_waitcnt vmcnt(8)" ::: "memory")
#define VMCNT0() asm volatile("s_waitcnt vmcnt(0)" ::: "memory")

__device__ __forceinline__ void gload_lds16(const bf16* g, bf16* l) {
  __builtin_amdgcn_global_load_lds(
      (const __attribute__((address_space(1))) unsigned int*)g,
      (__attribute__((address_space(3))) unsigned int*)l, 16, 0, 0);
}

// Stage one 128x64 K-tile (row-major, ld=1024) into a linear 16KB LDS slot,
// 256 threads (4 passes of 32 rows). Source col XOR-swizzled (rule 21).
__device__ __forceinline__ void stage_tile128_t256(const bf16* gbase, bf16* slot,
                                                   int t) {
#pragma unroll
  for (int p = 0; p < 4; ++p) {
    const int r = p * 32 + (t >> 3);
    const int c = ((t & 7) ^ (r & 7)) << 3;
    gload_lds16(gbase + (long)r * 1024 + c, slot + p * 2048 + t * 8);
  }
}

// Swizzled fragment read: logical (row, 16B-chunk c16) of a [128][64] slot.
__device__ __forceinline__ short8 lds_frag(const bf16* slot, int row, int c16) {
  return *(const short8*)(slot + row * 64 + ((c16 ^ (row & 7)) << 3));
}

// ======== 128x128-tile, BK=64, 256-thr, 64KiB, double-buffered counted-vmcnt
// K-loop (prep2-proven). Runs at 2 blocks/CU -> cross-block latency hiding.
// MODE 0: gv  — id<512: G = BT(xb, Mp); id>=512: V'^T = BT(Wp, xb_b). bf16 out.
// MODE 1: sc  — causal tiles, exp epilogue + part_l. bf16 out.
// MODE 2: pv  — NT=(bm+1)*2, linv-scaled fp32 out.
template <int MODE>
__global__ __launch_bounds__(256, 2) void gemm128(
    const bf16* __restrict__ xb, const bf16* __restrict__ Mp,
    const bf16* __restrict__ Wp, bf16* __restrict__ G, bf16* __restrict__ VT,
    const bf16* __restrict__ Pin, bf16* __restrict__ Pout,
    float* __restrict__ part_l, float* __restrict__ Out) {
  __shared__ bf16 smem[32768];  // 64 KiB: A[2] + B[2] slots of 128x64
  const int id = blockIdx.x;
  const int t = threadIdx.x;
  const int lane = t & 63;
  const int wid = t >> 6;
  const int wr = (wid >> 1) * 64;
  const int wc = (wid & 1) * 64;
  const int lr = lane & 15;
  const int c16 = lane >> 4;
  const long SS = 1024L * 1024;

  const bf16 *Ag, *Bg;
  int arow, bcol, NT = 16, bz = 0, bm = 0, bn = 0;
  if (MODE == 0) {
    if (id < 512) {
      // G: bm 0..63 (XCD-affine: same-XCD blocks share 8 A-panels), bn 0..7
      bm = (id & 7) + 8 * ((id >> 3) & 7);
      bn = id >> 6;
      arow = bm * 128;
      bcol = bn * 128;
      Ag = xb + (long)arow * 1024;
      Bg = Mp + (long)bcol * 1024;
    } else {
      const int v = id - 512;
      bz = v & 7;                      // one batch per XCD
      const int gs = (v >> 3) & 7;
      const int ss = v >> 6;
      arow = gs * 128;
      bcol = ss * 128;
      Ag = Wp + (long)arow * 1024;
      Bg = xb + (long)bz * SS + (long)bcol * 1024;
    }
  } else if (MODE == 1) {
    bz = id & 7;
    int rr = id >> 3;                  // 0..35 triangular
    while (rr >= bm + 1) { rr -= bm + 1; ++bm; }
    bn = rr;                           // bn <= bm
    arow = bm * 128;
    bcol = bn * 128;
    Ag = G + (long)bz * SS + (long)arow * 1024;
    Bg = xb + (long)bz * SS + (long)bcol * 1024;
  } else {
    bz = id & 7;
    const int w = id >> 3;
    bm = w & 7;
    bn = w >> 3;
    NT = (bm + 1) * 2;                 // causal K-limit
    arow = bm * 128;
    bcol = bn * 128;
    Ag = Pin + (long)bz * SS + (long)arow * 1024;
    Bg = VT + (long)bz * SS + (long)bcol * 1024;
  }

  bf16* sA = smem;
  bf16* sB = smem + 16384;

  // prologue: tiles 0 and 1 (NT >= 2 always)
  stage_tile128_t256(Ag, sA, t);
  stage_tile128_t256(Bg, sB, t);
  stage_tile128_t256(Ag + 64, sA + 8192, t);
  stage_tile128_t256(Bg + 64, sB + 8192, t);
  VMCNT8();  // tile 0 landed; tile 1's 8 loads may stay in flight
  SBAR();

  f32x4 acc[4][4] = {};
  for (int tt = 0; tt < NT; ++tt) {
    const int cur = tt & 1;
    const bf16* As = sA + cur * 8192;
    const bf16* Bs = sB + cur * 8192;
    short8 a[4][2], b[4][2];
#pragma unroll
    for (int m = 0; m < 4; ++m)
#pragma unroll
      for (int ks = 0; ks < 2; ++ks)
        a[m][ks] = lds_frag(As, wr + m * 16 + lr, c16 + ks * 4);
#pragma unroll
    for (int n = 0; n < 4; ++n)
#pragma unroll
      for (int ks = 0; ks < 2; ++ks)
        b[n][ks] = lds_frag(Bs, wc + n * 16 + lr, c16 + ks * 4);
#pragma unroll
    for (int m = 0; m < 4; ++m)
#pragma unroll
      for (int n = 0; n < 4; ++n)
#pragma unroll
        for (int ks = 0; ks < 2; ++ks)
          acc[m][n] = __builtin_amdgcn_mfma_f32_16x16x32_bf16(
              a[m][ks], b[n][ks], acc[m][n], 0, 0, 0);
    SBAR();  // all waves' reads of slot cur have completed (lgkm before MFMA)
    if (tt + 2 < NT) {
      stage_tile128_t256(Ag + (tt + 2) * 64, sA + cur * 8192, t);
      stage_tile128_t256(Bg + (tt + 2) * 64, sB + cur * 8192, t);
      VMCNT8();  // tile tt+1 landed; tt+2 stays in flight
    } else if (tt + 1 < NT) {
      VMCNT0();
    }
    SBAR();
  }

  const int r0 = (lane >> 4) * 4;
  if (MODE == 0) {
    bf16* C = (id < 512) ? G : (VT + (long)bz * SS);
#pragma unroll
    for (int m = 0; m < 4; ++m)
#pragma unroll
      for (int n = 0; n < 4; ++n)
#pragma unroll
        for (int r = 0; r < 4; ++r)
          C[(long)(arow + wr + m * 16 + r0 + r) * 1024 + bcol + wc + n * 16 + lr] =
              __float2bfloat16(acc[m][n][r]);
  } else if (MODE == 1) {
    // exp + causal mask + store + deterministic per-row partial sums
    bf16* C = Pout + (long)bz * SS;
    float rsum[4][4];
#pragma unroll
    for (int m = 0; m < 4; ++m)
#pragma unroll
      for (int r = 0; r < 4; ++r) rsum[m][r] = 0.f;
#pragma unroll
    for (int m = 0; m < 4; ++m)
#pragma unroll
      for (int n = 0; n < 4; ++n)
#pragma unroll
        for (int r = 0; r < 4; ++r) {
          const int row = arow + wr + m * 16 + r0 + r;
          const int col = bcol + wc + n * 16 + lr;
          const float e = (col <= row) ? __expf(acc[m][n][r] * 0.03125f) : 0.f;
          C[(long)row * 1024 + col] = __float2bfloat16(e);
          rsum[m][r] += e;
        }
#pragma unroll
    for (int m = 0; m < 4; ++m)
#pragma unroll
      for (int r = 0; r < 4; ++r) {
#pragma unroll
        for (int o = 1; o < 16; o <<= 1)
          rsum[m][r] += __shfl_xor(rsum[m][r], o, 64);
      }
    float* wsum = (float*)smem;  // [2 wc][128 rows]; LDS free after final SBAR
    if (lr == 0) {
#pragma unroll
      for (int m = 0; m < 4; ++m)
#pragma unroll
        for (int r = 0; r < 4; ++r)
          wsum[(wid & 1) * 128 + wr + m * 16 + (lane >> 4) * 4 + r] = rsum[m][r];
    }
    __syncthreads();
    if (t < 128)
      part_l[(((long)bz * 8 + bm) * 8 + bn) * 128 + t] = wsum[t] + wsum[128 + t];
  } else {
    float* linv = (float*)smem;  // LDS free after final SBAR
    if (t < 128) {
      float l = 0.f;
      for (int j = 0; j <= bm; ++j)
        l += part_l[(((long)bz * 8 + bm) * 8 + j) * 128 + t];
      linv[t] = 1.f / l;
    }
    __syncthreads();
    float* C = Out + (long)bz * SS;
#pragma unroll
    for (int m = 0; m < 4; ++m)
#pragma unroll
      for (int r = 0; r < 4; ++r) {
        const int rl = wr + m * 16 + r0 + r;
        const float s = linv[rl];
#pragma unroll
        for (int n = 0; n < 4; ++n)
          C[(long)(arow + rl) * 1024 + bcol + wc + n * 16 + lr] =
              acc[m][n][r] * s;
      }
  }
}

// ---------------- prep2: full-K small GEMMs (blocks 0-127) overlapped with
// x fp32->bf16 conversion (blocks 128-4223).
__global__ __launch_bounds__(256, 2) void prep2(
    const bf16* __restrict__ wkT, const bf16* __restrict__ wqT,
    const bf16* __restrict__ wo, const bf16* __restrict__ wvT,
    bf16* __restrict__ Mp, bf16* __restrict__ Wp, const float* __restrict__ x,
    bf16* __restrict__ xb) {
  __shared__ bf16 smem[32768];
  const int bid = blockIdx.x;
  const int t = threadIdx.x;

  if (bid >= 128) {  // x conversion
    const long i = (long)(bid - 128) * 2048 + t * 8;
    const float4 a = *(const float4*)&x[i];
    const float4 b = *(const float4*)&x[i + 4];
    const float va[8] = {a.x, a.y, a.z, a.w, b.x, b.y, b.z, b.w};
    union { bf16 h; short s; } u;
    short8 o;
#pragma unroll
    for (int j = 0; j < 8; ++j) { u.h = __float2bfloat16(va[j]); o[j] = u.s; }
    *(short8*)&xb[i] = o;
    return;
  }

  const int mat = bid >> 6;
  const int tile = bid & 63;
  const int bm = tile >> 3, bn = tile & 7;
  const bf16* A = (mat == 0) ? wkT : wo;
  const bf16* B = (mat == 0) ? wqT : wvT;
  bf16* C = (mat == 0) ? Mp : Wp;

  const int lane = t & 63;
  const int wid = t >> 6;
  const int wr = (wid >> 1) * 64;
  const int wc = (wid & 1) * 64;
  const int lr = lane & 15;
  const int c16 = lane >> 4;
  const int arow = bm * 128;
  const int brow = bn * 128;
  const bf16* Ag = A + (long)arow * 1024;
  const bf16* Bg = B + (long)brow * 1024;
  bf16* sA = smem;
  bf16* sB = smem + 16384;

  stage_tile128_t256(Ag, sA, t);
  stage_tile128_t256(Bg, sB, t);
  stage_tile128_t256(Ag + 64, sA + 8192, t);
  stage_tile128_t256(Bg + 64, sB + 8192, t);
  VMCNT8();
  SBAR();

  f32x4 acc[4][4] = {};
  for (int tt = 0; tt < 16; ++tt) {
    const int cur = tt & 1;
    const bf16* As = sA + cur * 8192;
    const bf16* Bs = sB + cur * 8192;
    short8 a[4][2], b[4][2];
#pragma unroll
    for (int m = 0; m < 4; ++m)
#pragma unroll
      for (int ks = 0; ks < 2; ++ks)
        a[m][ks] = lds_frag(As, wr + m * 16 + lr, c16 + ks * 4);
#pragma unroll
    for (int n = 0; n < 4; ++n)
#pragma unroll
      for (int ks = 0; ks < 2; ++ks)
        b[n][ks] = lds_frag(Bs, wc + n * 16 + lr, c16 + ks * 4);
#pragma unroll
    for (int m = 0; m < 4; ++m)
#pragma unroll
      for (int n = 0; n < 4; ++n)
#pragma unroll
        for (int ks = 0; ks < 2; ++ks)
          acc[m][n] = __builtin_amdgcn_mfma_f32_16x16x32_bf16(
              a[m][ks], b[n][ks], acc[m][n], 0, 0, 0);
    SBAR();
    if (tt + 2 < 16) {
      stage_tile128_t256(Ag + (tt + 2) * 64, sA + cur * 8192, t);
      stage_tile128_t256(Bg + (tt + 2) * 64, sB + cur * 8192, t);
      VMCNT8();
    } else if (tt + 1 < 16) {
      VMCNT0();
    }
    SBAR();
  }

#pragma unroll
  for (int m = 0; m < 4; ++m)
#pragma unroll
    for (int n = 0; n < 4; ++n)
#pragma unroll
      for (int r = 0; r < 4; ++r) {
        const int row = arow + wr + m * 16 + (lane >> 4) * 4 + r;
        const int col = brow + wc + n * 16 + lr;
        C[(long)row * 1024 + col] = __float2bfloat16(acc[m][n][r]);
      }
}

// fp32 -> bf16 weights: wq, wk, wv transposed (64x64 LDS tiles); wo plain.
__global__ __launch_bounds__(256) void f2bw(
    const float* __restrict__ wq, const float* __restrict__ wk,
    const float* __restrict__ wv, const float* __restrict__ wo,
    bf16* __restrict__ wqTb, bf16* __restrict__ wkTb,
    bf16* __restrict__ wvTb, bf16* __restrict__ wob) {
  __shared__ float T[64][65];
  const int bid = blockIdx.x;
  const int t = threadIdx.x;
  union { bf16 h; short s; } u;

  if (bid < 768) {
    const int mat = bid >> 8;
    const int tile = bid & 255;
    const int er = tile >> 4, dc = tile & 15;
    const float* src = ((mat == 0) ? wq : (mat == 1) ? wk : wv);
    bf16* dstb = ((mat == 0) ? wqTb : (mat == 1) ? wkTb : wvTb);
    const int r = t >> 2, c = (t & 3) * 16;
    const float* s0 = src + (long)(er * 64 + r) * 1024 + dc * 64 + c;
#pragma unroll
    for (int j = 0; j < 4; ++j) {
      const float4 v = *(const float4*)(s0 + j * 4);
      T[r][c + j * 4 + 0] = v.x;
      T[r][c + j * 4 + 1] = v.y;
      T[r][c + j * 4 + 2] = v.z;
      T[r][c + j * 4 + 3] = v.w;
    }
    __syncthreads();
    const int d = t >> 2, ec = (t & 3) * 16;
    bf16* dst = dstb + (long)(dc * 64 + d) * 1024 + er * 64 + ec;
#pragma unroll
    for (int half = 0; half < 2; ++half) {
      short8 o;
#pragma unroll
      for (int j = 0; j < 8; ++j) {
        u.h = __float2bfloat16(T[ec + half * 8 + j][d]);
        o[j] = u.s;
      }
      *(short8*)(dst + half * 8) = o;
    }
    return;
  }
  const long i = (long)(bid - 768) * 2048 + t * 8;
  const float4 a = *(const float4*)&wo[i];
  const float4 b = *(const float4*)&wo[i + 4];
  const float va[8] = {a.x, a.y, a.z, a.w, b.x, b.y, b.z, b.w};
  short8 o;
#pragma unroll
  for (int j = 0; j < 8; ++j) { u.h = __float2bfloat16(va[j]); o[j] = u.s; }
  *(short8*)&wob[i] = o;
}

extern "C" void kernel_launch(void* const* d_in, const int* in_sizes, int n_in,
                              void* d_out, int out_size, void* d_ws, size_t ws_size,
                              hipStream_t stream) {
  (void)in_sizes; (void)n_in; (void)out_size; (void)ws_size;
  const float* x  = (const float*)d_in[0];
  const float* wq = (const float*)d_in[1];
  const float* wk = (const float*)d_in[2];
  const float* wv = (const float*)d_in[3];
  const float* wo = (const float*)d_in[4];
  float* out = (float*)d_out;
  bf16* ws = (bf16*)d_ws;

  const long SB = 8192L * 1024;
  const long SW = 1024L * 1024;

  bf16* xb   = ws;                    // [8][s][d]
  bf16* wqTb = ws + SB;               // wq^T [d][e]
  bf16* wkTb = ws + SB + SW;          // wk^T [d][e]
  bf16* wvTb = ws + SB + 2 * SW;      // wv^T [d][e]
  bf16* wob  = ws + SB + 3 * SW;      // wo   [g][e]
  bf16* Mp   = ws + SB + 4 * SW;      // M' = wq^T wk
  bf16* Wp   = ws + SB + 5 * SW;      // W' = wo wv
  bf16* G    = ws + SB + 6 * SW;      // [8192][1024]
  bf16* VT   = G + SB;                // V'^T [8][g][s]
  bf16* P    = VT + SB;               // unnormalized P~
  float* part_l = (float*)(P + SB);   // [8][8][8][128] row partial sums

  f2bw<<<dim3(1280), dim3(256), 0, stream>>>(wq, wk, wv, wo, wqTb, wkTb, wvTb, wob);
  prep2<<<dim3(4224), dim3(256), 0, stream>>>(wkTb, wqTb, wob, wvTb, Mp, Wp, x, xb);
  // G and V'^T: 1024 blocks at 2/CU = 2 exact rounds
  gemm128<0><<<dim3(1024), dim3(256), 0, stream>>>(xb, Mp, Wp, G, VT,
                                                   nullptr, nullptr, nullptr, nullptr);
  // scores + exp + mask + partial sums: 288 causal blocks
  gemm128<1><<<dim3(288), dim3(256), 0, stream>>>(xb, nullptr, nullptr, G, nullptr,
                                                  nullptr, P, part_l, nullptr);
  // out = (P~ @ V') / l: 512 blocks, causal K-limit
  gemm128<2><<<dim3(512), dim3(256), 0, stream>>>(nullptr, nullptr, nullptr, nullptr,
                                                  VT, P, nullptr, part_l, out);
}